// Round 1
// baseline (29617.157 us; speedup 1.0000x reference)
//
#include <hip/hip_runtime.h>
#include <math.h>

#define L_ 8
#define H_ 16
#define E_ 1024
#define V_ 32000
#define B_ 4
#define T_ 1024
#define HS_ 64
#define M_ 4096   // B*T

// ---------------------------------------------------------------- embed
__global__ __launch_bounds__(256) void k_embed(
    const int* __restrict__ idx, const float* __restrict__ tok,
    const float* __restrict__ pos, float* __restrict__ x) {
  int bt = blockIdx.x;              // 0..4095
  int t  = bt & (T_ - 1);
  int token = idx[bt];
  const float4* te = (const float4*)(tok + (size_t)token * E_);
  const float4* pe = (const float4*)(pos + (size_t)t * E_);
  float4* xo = (float4*)(x + (size_t)bt * E_);
  int i = threadIdx.x;              // 0..255, E/4 = 256 float4
  float4 a = te[i], b = pe[i];
  xo[i] = make_float4(a.x + b.x, a.y + b.y, a.z + b.z, a.w + b.w);
}

// ---------------------------------------------------------------- layernorm
__device__ __forceinline__ float blk_sum256(float v, float* red) {
  #pragma unroll
  for (int o = 1; o < 64; o <<= 1) v += __shfl_xor(v, o);
  int wid = threadIdx.x >> 6, lane = threadIdx.x & 63;
  if (lane == 0) red[wid] = v;
  __syncthreads();
  v = red[0] + red[1] + red[2] + red[3];
  __syncthreads();
  return v;
}

__global__ __launch_bounds__(256) void k_ln(
    const float* __restrict__ X, const float* __restrict__ g,
    const float* __restrict__ b, float* __restrict__ Y) {
  __shared__ float red[4];
  int row = blockIdx.x;
  int i = threadIdx.x;              // 256 threads x 4 floats
  float4 xv = ((const float4*)(X + (size_t)row * E_))[i];
  float s = xv.x + xv.y + xv.z + xv.w;
  s = blk_sum256(s, red);
  float mean = s * (1.0f / E_);
  float dx = xv.x - mean, dy = xv.y - mean, dz = xv.z - mean, dw = xv.w - mean;
  float vs = dx*dx + dy*dy + dz*dz + dw*dw;
  vs = blk_sum256(vs, red);
  float rstd = rsqrtf(vs * (1.0f / E_) + 1e-5f);
  float4 gv = ((const float4*)g)[i];
  float4 bv = ((const float4*)b)[i];
  float4 o;
  o.x = dx * rstd * gv.x + bv.x;
  o.y = dy * rstd * gv.y + bv.y;
  o.z = dz * rstd * gv.z + bv.z;
  o.w = dw * rstd * gv.w + bv.w;
  ((float4*)(Y + (size_t)row * E_))[i] = o;
}

// ---------------------------------------------------------------- fp32 GEMM
// C[M,N] = A[M,K] @ W[K,N] (+bias) (+relu) (+residual R)
// 64x64 tile, BK=16, 256 threads, 4x4 outputs/thread.
template<bool RELU, bool RES>
__global__ __launch_bounds__(256) void k_gemm(
    const float* __restrict__ A, const float* __restrict__ W,
    const float* __restrict__ bias, const float* __restrict__ R,
    float* __restrict__ C, int M, int N, int K) {
  __shared__ float As[16][68];   // [k][m], pad keeps 16B align (68*4=272, 272%16==0)
  __shared__ float Bs[16][68];   // [k][n]
  int tid = threadIdx.x;
  int tx = tid & 15, ty = tid >> 4;
  int m0 = blockIdx.y * 64;
  int n0 = blockIdx.x * 64;
  int ar = tid >> 2;              // 0..63 (tile row)
  int ak = (tid & 3) * 4;         // 0,4,8,12 (tile k)
  int br = tid >> 4;              // 0..15 (tile k)
  int bc = (tid & 15) * 4;        // 0..60 (tile col)
  float acc[4][4] = {};
  for (int k0 = 0; k0 < K; k0 += 16) {
    float4 av = *(const float4*)(A + (size_t)(m0 + ar) * K + k0 + ak);
    float4 bv = *(const float4*)(W + (size_t)(k0 + br) * N + n0 + bc);
    __syncthreads();
    As[ak + 0][ar] = av.x; As[ak + 1][ar] = av.y;
    As[ak + 2][ar] = av.z; As[ak + 3][ar] = av.w;
    *(float4*)&Bs[br][bc] = bv;
    __syncthreads();
    #pragma unroll
    for (int kk = 0; kk < 16; ++kk) {
      float4 a = *(const float4*)&As[kk][ty * 4];
      float4 b = *(const float4*)&Bs[kk][tx * 4];
      acc[0][0] += a.x * b.x; acc[0][1] += a.x * b.y; acc[0][2] += a.x * b.z; acc[0][3] += a.x * b.w;
      acc[1][0] += a.y * b.x; acc[1][1] += a.y * b.y; acc[1][2] += a.y * b.z; acc[1][3] += a.y * b.w;
      acc[2][0] += a.z * b.x; acc[2][1] += a.z * b.y; acc[2][2] += a.z * b.z; acc[2][3] += a.z * b.w;
      acc[3][0] += a.w * b.x; acc[3][1] += a.w * b.y; acc[3][2] += a.w * b.z; acc[3][3] += a.w * b.w;
    }
  }
  #pragma unroll
  for (int i = 0; i < 4; ++i) {
    size_t row = (size_t)(m0 + ty * 4 + i);
    #pragma unroll
    for (int j = 0; j < 4; ++j) {
      int col = n0 + tx * 4 + j;
      float vv = acc[i][j];
      if (bias) vv += bias[col];
      if (RELU) vv = fmaxf(vv, 0.0f);
      if (RES)  vv += R[row * N + col];
      C[row * N + col] = vv;
    }
  }
}

// ---------------------------------------------------------------- attention
// One block per (query row, b*h). Q/K/V in [B,T,E] layout, head h at cols h*64..h*64+63.
__global__ __launch_bounds__(256) void k_attn(
    const float* __restrict__ Q, const float* __restrict__ K,
    const float* __restrict__ Vv, float* __restrict__ O) {
  int qi = blockIdx.x;
  int bh = blockIdx.y;
  int b = bh >> 4;          // /H
  int h = bh & 15;
  __shared__ float s[T_];
  __shared__ float qs[HS_];
  __shared__ float red[4];
  __shared__ float op[4][HS_];
  int tid = threadIdx.x;
  int wid = tid >> 6, lane = tid & 63;
  size_t rowq = ((size_t)(b * T_ + qi)) * E_ + h * HS_;
  if (tid < 16) ((float4*)qs)[tid] = *(const float4*)(Q + rowq + tid * 4);
  __syncthreads();
  int nk = qi + 1;
  const float scale = 0.03125f;     // E^-0.5 = 1/32 (reference scales by C, not hs)
  float lmax = -1e30f;
  for (int kk = tid; kk < nk; kk += 256) {
    const float* kr = K + ((size_t)(b * T_ + kk)) * E_ + h * HS_;
    float d = 0.0f;
    #pragma unroll
    for (int j = 0; j < 16; ++j) {
      float4 kv = *(const float4*)(kr + j * 4);
      float4 qv = *(const float4*)(qs + j * 4);
      d += kv.x * qv.x + kv.y * qv.y + kv.z * qv.z + kv.w * qv.w;
    }
    d *= scale;
    s[kk] = d;
    lmax = fmaxf(lmax, d);
  }
  #pragma unroll
  for (int o = 1; o < 64; o <<= 1) lmax = fmaxf(lmax, __shfl_xor(lmax, o));
  __syncthreads();                      // s[] writes done
  if (lane == 0) red[wid] = lmax;
  __syncthreads();
  lmax = fmaxf(fmaxf(red[0], red[1]), fmaxf(red[2], red[3]));
  float lsum = 0.0f;
  for (int kk = tid; kk < nk; kk += 256) {
    float p = expf(s[kk] - lmax);
    s[kk] = p;
    lsum += p;
  }
  #pragma unroll
  for (int o = 1; o < 64; o <<= 1) lsum += __shfl_xor(lsum, o);
  __syncthreads();                      // red reads done + s[] rewrites done
  if (lane == 0) red[wid] = lsum;
  __syncthreads();
  lsum = red[0] + red[1] + red[2] + red[3];
  float rinv = 1.0f / lsum;
  // phase 3: out[d] = sum_k p[k]*V[k,d]; thread t: d=t&63, key-chunk c=t>>6
  int d = tid & 63, c = tid >> 6;
  float acc = 0.0f;
  for (int kk = c; kk < nk; kk += 4) {
    acc += s[kk] * Vv[((size_t)(b * T_ + kk)) * E_ + h * HS_ + d];
  }
  op[c][d] = acc;
  __syncthreads();
  if (tid < 64) {
    float o = (op[0][tid] + op[1][tid] + op[2][tid] + op[3][tid]) * rinv;
    O[((size_t)(b * T_ + qi)) * E_ + h * HS_ + tid] = o;
  }
}

// ---------------------------------------------------------------- launch
extern "C" void kernel_launch(void* const* d_in, const int* in_sizes, int n_in,
                              void* d_out, int out_size, void* d_ws, size_t ws_size,
                              hipStream_t stream) {
  const int*   idx  = (const int*)d_in[0];
  const float* tok  = (const float*)d_in[1];
  const float* pos  = (const float*)d_in[2];
  const float* ln1g = (const float*)d_in[3];
  const float* ln1b = (const float*)d_in[4];
  const float* Wq   = (const float*)d_in[5];
  const float* Wk   = (const float*)d_in[6];
  const float* Wv   = (const float*)d_in[7];
  const float* Wo   = (const float*)d_in[8];
  const float* bo   = (const float*)d_in[9];
  const float* ln2g = (const float*)d_in[10];
  const float* ln2b = (const float*)d_in[11];
  const float* W1   = (const float*)d_in[12];
  const float* b1   = (const float*)d_in[13];
  const float* W2   = (const float*)d_in[14];
  const float* b2   = (const float*)d_in[15];
  const float* lnfg = (const float*)d_in[16];
  const float* lnfb = (const float*)d_in[17];
  const float* Wlm  = (const float*)d_in[18];
  const float* blm  = (const float*)d_in[19];
  float* out = (float*)d_out;

  const size_t A = (size_t)M_ * E_;          // 4M floats per activation buffer
  float* ws = (float*)d_ws;
  float *x, *h, *qb, *kb, *vb, *ob, *mh;
  size_t need_bytes = 10 * A * sizeof(float);   // x,h,q,k,v,o (6A) + mh (4A)
  if (ws_size >= need_bytes) {
    x = ws; h = ws + A; qb = ws + 2*A; kb = ws + 3*A; vb = ws + 4*A;
    ob = ws + 5*A; mh = ws + 6*A;
  } else {
    // fall back: per-layer temporaries live in d_out (dead before final GEMM writes it)
    x = ws; h = ws + A;
    float* scr = (float*)d_out;
    qb = scr; kb = scr + A; vb = scr + 2*A; ob = scr + 3*A; mh = scr + 4*A;
  }

  k_embed<<<M_, 256, 0, stream>>>(idx, tok, pos, x);
  dim3 gE(E_/64, M_/64);          // N=1024 GEMMs
  dim3 gF(4*E_/64, M_/64);        // N=4096 GEMM
  dim3 gV(V_/64, M_/64);          // N=32000 GEMM
  for (int l = 0; l < L_; ++l) {
    size_t wOff  = (size_t)l * E_ * E_;
    size_t w1Off = (size_t)l * E_ * 4 * E_;
    k_ln<<<M_, 256, 0, stream>>>(x, ln1g + l*E_, ln1b + l*E_, h);
    k_gemm<false,false><<<gE, 256, 0, stream>>>(h, Wq + wOff, nullptr, nullptr, qb, M_, E_, E_);
    k_gemm<false,false><<<gE, 256, 0, stream>>>(h, Wk + wOff, nullptr, nullptr, kb, M_, E_, E_);
    k_gemm<false,false><<<gE, 256, 0, stream>>>(h, Wv + wOff, nullptr, nullptr, vb, M_, E_, E_);
    k_attn<<<dim3(T_, B_*H_), 256, 0, stream>>>(qb, kb, vb, ob);
    k_gemm<false,true><<<gE, 256, 0, stream>>>(ob, Wo + wOff, bo + l*E_, x, x, M_, E_, E_);
    k_ln<<<M_, 256, 0, stream>>>(x, ln2g + l*E_, ln2b + l*E_, h);
    k_gemm<true,false><<<gF, 256, 0, stream>>>(h, W1 + w1Off, b1 + (size_t)l*4*E_, nullptr, mh, M_, 4*E_, E_);
    k_gemm<false,true><<<gE, 256, 0, stream>>>(mh, W2 + w1Off, b2 + l*E_, x, x, M_, E_, 4*E_);
  }
  k_ln<<<M_, 256, 0, stream>>>(x, lnfg, lnfb, h);
  k_gemm<false,false><<<gV, 256, 0, stream>>>(h, Wlm, blm, nullptr, out, M_, V_, E_);
}

// Round 2
// 18050.107 us; speedup vs baseline: 1.6408x; 1.6408x over previous
//
#include <hip/hip_runtime.h>
#include <math.h>

#define L_ 8
#define H_ 16
#define E_ 1024
#define V_ 32000
#define B_ 4
#define T_ 1024
#define HS_ 64
#define M_ 4096   // B*T

typedef __attribute__((ext_vector_type(8))) short short8;
typedef __attribute__((ext_vector_type(4))) float f32x4;

__device__ __forceinline__ unsigned short f2bf(float f) {
  unsigned int u = __builtin_bit_cast(unsigned int, f);
  u += 0x7fffu + ((u >> 16) & 1u);          // RNE
  return (unsigned short)(u >> 16);
}

// ---------------------------------------------------------------- embed (fp32 x)
__global__ __launch_bounds__(256) void k_embed(
    const int* __restrict__ idx, const float* __restrict__ tok,
    const float* __restrict__ pos, float* __restrict__ x) {
  int bt = blockIdx.x;
  int t  = bt & (T_ - 1);
  int token = idx[bt];
  const float4* te = (const float4*)(tok + (size_t)token * E_);
  const float4* pe = (const float4*)(pos + (size_t)t * E_);
  float4* xo = (float4*)(x + (size_t)bt * E_);
  int i = threadIdx.x;
  float4 a = te[i], b = pe[i];
  xo[i] = make_float4(a.x + b.x, a.y + b.y, a.z + b.z, a.w + b.w);
}

// ---------------------------------------------------------------- layernorm (fp32 in, bf16 out)
__device__ __forceinline__ float blk_sum256(float v, float* red) {
  #pragma unroll
  for (int o = 1; o < 64; o <<= 1) v += __shfl_xor(v, o);
  int wid = threadIdx.x >> 6, lane = threadIdx.x & 63;
  if (lane == 0) red[wid] = v;
  __syncthreads();
  v = red[0] + red[1] + red[2] + red[3];
  __syncthreads();
  return v;
}

__global__ __launch_bounds__(256) void k_ln_bf(
    const float* __restrict__ X, const float* __restrict__ g,
    const float* __restrict__ b, unsigned short* __restrict__ Y) {
  __shared__ float red[4];
  int row = blockIdx.x;
  int i = threadIdx.x;
  float4 xv = ((const float4*)(X + (size_t)row * E_))[i];
  float s = xv.x + xv.y + xv.z + xv.w;
  s = blk_sum256(s, red);
  float mean = s * (1.0f / E_);
  float dx = xv.x - mean, dy = xv.y - mean, dz = xv.z - mean, dw = xv.w - mean;
  float vs = dx*dx + dy*dy + dz*dz + dw*dw;
  vs = blk_sum256(vs, red);
  float rstd = rsqrtf(vs * (1.0f / E_) + 1e-5f);
  float4 gv = ((const float4*)g)[i];
  float4 bv = ((const float4*)b)[i];
  ushort4 o;
  o.x = f2bf(dx * rstd * gv.x + bv.x);
  o.y = f2bf(dy * rstd * gv.y + bv.y);
  o.z = f2bf(dz * rstd * gv.z + bv.z);
  o.w = f2bf(dw * rstd * gv.w + bv.w);
  ((ushort4*)(Y + (size_t)row * E_))[i] = o;
}

// ---------------------------------------------------------------- bf16 MFMA GEMM
// C[M,N] = A[M,K](bf16) @ W[K,N](f32, converted in staging) (+bias)(+relu)(+res f32)
// 128x128 tile, BK=32, 256 threads = 4 waves (2x2), each wave 64x64 (4x4 frags of 16x16).
// OT: 0 = fp32 out, 1 = bf16 out.
template<int OT, bool RELU, bool RES>
__global__ __launch_bounds__(256) void k_gemm_bf(
    const unsigned short* __restrict__ A, const float* __restrict__ W,
    const float* __restrict__ bias, const float* __restrict__ R,
    void* __restrict__ Cout, int M, int N, int K) {
  __shared__ unsigned short As[128][40];   // [m][k], pad 32->40 (80B rows) spreads banks
  __shared__ unsigned short Bs[128][40];   // [n][k]
  int tid = threadIdx.x;
  int lane = tid & 63, wid = tid >> 6;
  int m0 = blockIdx.x * 128, n0 = blockIdx.y * 128;
  int wr = (wid >> 1) * 64, wc = (wid & 1) * 64;
  f32x4 acc[4][4] = {};

  int a_row = tid >> 1, a_koff = (tid & 1) * 16;     // 16 bf16 per thread
  int b_nb = tid & 31, b_kb = (tid >> 5) * 4;        // 4 n (stride 32) x 4 k per thread

  int lr = lane & 15, lq = lane >> 4;                 // frag row/col + k-chunk

  for (int k0 = 0; k0 < K; k0 += 32) {
    const unsigned short* ap = A + (size_t)(m0 + a_row) * K + k0 + a_koff;
    uint4 av0 = *(const uint4*)ap;
    uint4 av1 = *(const uint4*)(ap + 8);
    float wv[4][4];
    #pragma unroll
    for (int dk = 0; dk < 4; ++dk) {
      const float* wrow = W + (size_t)(k0 + b_kb + dk) * N + n0 + b_nb;
      #pragma unroll
      for (int j = 0; j < 4; ++j) wv[j][dk] = wrow[32 * j];
    }
    __syncthreads();
    *(uint4*)&As[a_row][a_koff]     = av0;
    *(uint4*)&As[a_row][a_koff + 8] = av1;
    #pragma unroll
    for (int j = 0; j < 4; ++j) {
      ushort4 pk;
      pk.x = f2bf(wv[j][0]); pk.y = f2bf(wv[j][1]);
      pk.z = f2bf(wv[j][2]); pk.w = f2bf(wv[j][3]);
      *(ushort4*)&Bs[b_nb + 32 * j][b_kb] = pk;
    }
    __syncthreads();
    short8 af[4], bf[4];
    #pragma unroll
    for (int m = 0; m < 4; ++m) af[m] = *(const short8*)&As[wr + m * 16 + lr][lq * 8];
    #pragma unroll
    for (int n = 0; n < 4; ++n) bf[n] = *(const short8*)&Bs[wc + n * 16 + lr][lq * 8];
    #pragma unroll
    for (int m = 0; m < 4; ++m)
      #pragma unroll
      for (int n = 0; n < 4; ++n)
        acc[m][n] = __builtin_amdgcn_mfma_f32_16x16x32_bf16(af[m], bf[n], acc[m][n], 0, 0, 0);
  }

  // epilogue: C row = (lane>>4)*4 + i, col = lane&15  (measured m89/m91 layout)
  #pragma unroll
  for (int m = 0; m < 4; ++m) {
    #pragma unroll
    for (int n = 0; n < 4; ++n) {
      int col = n0 + wc + n * 16 + lr;
      float bv = bias ? bias[col] : 0.0f;
      #pragma unroll
      for (int i = 0; i < 4; ++i) {
        size_t row = (size_t)(m0 + wr + m * 16 + lq * 4 + i);
        float v = acc[m][n][i] + bv;
        if (RELU) v = fmaxf(v, 0.0f);
        if (RES)  v += R[row * N + col];
        if (OT == 0) ((float*)Cout)[row * N + col] = v;
        else ((unsigned short*)Cout)[row * N + col] = f2bf(v);
      }
    }
  }
}

// ---------------------------------------------------------------- attention (fp32 in, bf16 out)
__global__ __launch_bounds__(256) void k_attn(
    const float* __restrict__ Q, const float* __restrict__ K,
    const float* __restrict__ Vv, unsigned short* __restrict__ O) {
  int qi = blockIdx.x;
  int bh = blockIdx.y;
  int b = bh >> 4;
  int h = bh & 15;
  __shared__ float s[T_];
  __shared__ float qs[HS_];
  __shared__ float red[4];
  __shared__ float op[4][HS_];
  int tid = threadIdx.x;
  int wid = tid >> 6, lane = tid & 63;
  size_t rowq = ((size_t)(b * T_ + qi)) * E_ + h * HS_;
  if (tid < 16) ((float4*)qs)[tid] = *(const float4*)(Q + rowq + tid * 4);
  __syncthreads();
  int nk = qi + 1;
  const float scale = 0.03125f;     // E^-0.5 (reference scales by C, not hs)
  float lmax = -1e30f;
  for (int kk = tid; kk < nk; kk += 256) {
    const float* kr = K + ((size_t)(b * T_ + kk)) * E_ + h * HS_;
    float d = 0.0f;
    #pragma unroll
    for (int j = 0; j < 16; ++j) {
      float4 kv = *(const float4*)(kr + j * 4);
      float4 qv = *(const float4*)(qs + j * 4);
      d += kv.x * qv.x + kv.y * qv.y + kv.z * qv.z + kv.w * qv.w;
    }
    d *= scale;
    s[kk] = d;
    lmax = fmaxf(lmax, d);
  }
  #pragma unroll
  for (int o = 1; o < 64; o <<= 1) lmax = fmaxf(lmax, __shfl_xor(lmax, o));
  __syncthreads();
  if (lane == 0) red[wid] = lmax;
  __syncthreads();
  lmax = fmaxf(fmaxf(red[0], red[1]), fmaxf(red[2], red[3]));
  float lsum = 0.0f;
  for (int kk = tid; kk < nk; kk += 256) {
    float p = expf(s[kk] - lmax);
    s[kk] = p;
    lsum += p;
  }
  #pragma unroll
  for (int o = 1; o < 64; o <<= 1) lsum += __shfl_xor(lsum, o);
  __syncthreads();
  if (lane == 0) red[wid] = lsum;
  __syncthreads();
  lsum = red[0] + red[1] + red[2] + red[3];
  float rinv = 1.0f / lsum;
  int d = tid & 63, c = tid >> 6;
  float acc = 0.0f;
  for (int kk = c; kk < nk; kk += 4) {
    acc += s[kk] * Vv[((size_t)(b * T_ + kk)) * E_ + h * HS_ + d];
  }
  op[c][d] = acc;
  __syncthreads();
  if (tid < 64) {
    float o = (op[0][tid] + op[1][tid] + op[2][tid] + op[3][tid]) * rinv;
    O[((size_t)(b * T_ + qi)) * E_ + h * HS_ + tid] = f2bf(o);
  }
}

// ---------------------------------------------------------------- launch
extern "C" void kernel_launch(void* const* d_in, const int* in_sizes, int n_in,
                              void* d_out, int out_size, void* d_ws, size_t ws_size,
                              hipStream_t stream) {
  const int*   idx  = (const int*)d_in[0];
  const float* tok  = (const float*)d_in[1];
  const float* pos  = (const float*)d_in[2];
  const float* ln1g = (const float*)d_in[3];
  const float* ln1b = (const float*)d_in[4];
  const float* Wq   = (const float*)d_in[5];
  const float* Wk   = (const float*)d_in[6];
  const float* Wv   = (const float*)d_in[7];
  const float* Wo   = (const float*)d_in[8];
  const float* bo   = (const float*)d_in[9];
  const float* ln2g = (const float*)d_in[10];
  const float* ln2b = (const float*)d_in[11];
  const float* W1   = (const float*)d_in[12];
  const float* b1   = (const float*)d_in[13];
  const float* W2   = (const float*)d_in[14];
  const float* b2   = (const float*)d_in[15];
  const float* lnfg = (const float*)d_in[16];
  const float* lnfb = (const float*)d_in[17];
  const float* Wlm  = (const float*)d_in[18];
  const float* blm  = (const float*)d_in[19];

  // scratch: everything except h lives in d_out (dead before final GEMM writes it).
  // h (bf16 LN output) is read DURING the final GEMM -> must live in d_ws.
  char* scr = (char*)d_out;
  const size_t MB = 1024 * 1024;
  float*          xf = (float*)(scr);                 // 16MB fp32 residual stream
  float*          qf = (float*)(scr + 16 * MB);       // 16MB
  float*          kf = (float*)(scr + 32 * MB);       // 16MB
  float*          vf = (float*)(scr + 48 * MB);       // 16MB
  unsigned short* ob = (unsigned short*)(scr + 64 * MB); // 8MB bf16
  unsigned short* mh = (unsigned short*)(scr + 72 * MB); // 32MB bf16
  unsigned short* hb = (unsigned short*)d_ws;         // 8MB bf16 (survives into final GEMM)

  k_embed<<<M_, 256, 0, stream>>>(idx, tok, pos, xf);

  dim3 gE(M_ / 128, E_ / 128);        // N=1024
  dim3 gF(M_ / 128, 4 * E_ / 128);    // N=4096
  dim3 gV(M_ / 128, V_ / 128);        // N=32000

  for (int l = 0; l < L_; ++l) {
    size_t wOff  = (size_t)l * E_ * E_;
    size_t w1Off = (size_t)l * E_ * 4 * E_;
    k_ln_bf<<<M_, 256, 0, stream>>>(xf, ln1g + l * E_, ln1b + l * E_, hb);
    k_gemm_bf<0, false, false><<<gE, 256, 0, stream>>>(hb, Wq + wOff, nullptr, nullptr, qf, M_, E_, E_);
    k_gemm_bf<0, false, false><<<gE, 256, 0, stream>>>(hb, Wk + wOff, nullptr, nullptr, kf, M_, E_, E_);
    k_gemm_bf<0, false, false><<<gE, 256, 0, stream>>>(hb, Wv + wOff, nullptr, nullptr, vf, M_, E_, E_);
    k_attn<<<dim3(T_, B_ * H_), 256, 0, stream>>>(qf, kf, vf, ob);
    k_gemm_bf<0, false, true><<<gE, 256, 0, stream>>>(ob, Wo + wOff, bo + l * E_, xf, xf, M_, E_, E_);
    k_ln_bf<<<M_, 256, 0, stream>>>(xf, ln2g + l * E_, ln2b + l * E_, hb);
    k_gemm_bf<1, true, false><<<gF, 256, 0, stream>>>(hb, W1 + w1Off, b1 + (size_t)l * 4 * E_, nullptr, mh, M_, 4 * E_, E_);
    k_gemm_bf<0, false, true><<<gE, 256, 0, stream>>>(mh, W2 + w1Off, b2 + l * E_, xf, xf, M_, E_, 4 * E_);
  }
  k_ln_bf<<<M_, 256, 0, stream>>>(xf, lnfg, lnfb, hb);
  k_gemm_bf<0, false, false><<<gV, 256, 0, stream>>>(hb, Wlm, blm, nullptr, (float*)d_out, M_, V_, E_);
}

// Round 3
// 4390.217 us; speedup vs baseline: 6.7462x; 4.1114x over previous
//
#include <hip/hip_runtime.h>
#include <math.h>

#define L_ 8
#define H_ 16
#define E_ 1024
#define V_ 32000
#define B_ 4
#define T_ 1024
#define HS_ 64
#define M_ 4096   // B*T

typedef __attribute__((ext_vector_type(8))) short short8;
typedef __attribute__((ext_vector_type(4))) float f32x4;

__device__ __forceinline__ unsigned short f2bf(float f) {
  unsigned int u = __builtin_bit_cast(unsigned int, f);
  u += 0x7fffu + ((u >> 16) & 1u);          // RNE
  return (unsigned short)(u >> 16);
}

// ---------------------------------------------------------------- embed (fp32 x)
__global__ __launch_bounds__(256) void k_embed(
    const int* __restrict__ idx, const float* __restrict__ tok,
    const float* __restrict__ pos, float* __restrict__ x) {
  int bt = blockIdx.x;
  int t  = bt & (T_ - 1);
  int token = idx[bt];
  const float4* te = (const float4*)(tok + (size_t)token * E_);
  const float4* pe = (const float4*)(pos + (size_t)t * E_);
  float4* xo = (float4*)(x + (size_t)bt * E_);
  int i = threadIdx.x;
  float4 a = te[i], b = pe[i];
  xo[i] = make_float4(a.x + b.x, a.y + b.y, a.z + b.z, a.w + b.w);
}

// ---------------------------------------------------------------- layernorm (fp32 in, bf16 out)
__device__ __forceinline__ float blk_sum256(float v, float* red) {
  #pragma unroll
  for (int o = 1; o < 64; o <<= 1) v += __shfl_xor(v, o);
  int wid = threadIdx.x >> 6, lane = threadIdx.x & 63;
  if (lane == 0) red[wid] = v;
  __syncthreads();
  v = red[0] + red[1] + red[2] + red[3];
  __syncthreads();
  return v;
}

__global__ __launch_bounds__(256) void k_ln_bf(
    const float* __restrict__ X, const float* __restrict__ g,
    const float* __restrict__ b, unsigned short* __restrict__ Y) {
  __shared__ float red[4];
  int row = blockIdx.x;
  int i = threadIdx.x;
  float4 xv = ((const float4*)(X + (size_t)row * E_))[i];
  float s = xv.x + xv.y + xv.z + xv.w;
  s = blk_sum256(s, red);
  float mean = s * (1.0f / E_);
  float dx = xv.x - mean, dy = xv.y - mean, dz = xv.z - mean, dw = xv.w - mean;
  float vs = dx*dx + dy*dy + dz*dz + dw*dw;
  vs = blk_sum256(vs, red);
  float rstd = rsqrtf(vs * (1.0f / E_) + 1e-5f);
  float4 gv = ((const float4*)g)[i];
  float4 bv = ((const float4*)b)[i];
  ushort4 o;
  o.x = f2bf(dx * rstd * gv.x + bv.x);
  o.y = f2bf(dy * rstd * gv.y + bv.y);
  o.z = f2bf(dz * rstd * gv.z + bv.z);
  o.w = f2bf(dw * rstd * gv.w + bv.w);
  ((ushort4*)(Y + (size_t)row * E_))[i] = o;
}

// ---------------------------------------------------------------- bf16 MFMA GEMM
// C[M,N] = A[M,K](bf16) @ W[K,N](f32, converted in staging) (+bias)(+relu)(+res f32)
// 128x128 tile, BK=32, 256 threads = 4 waves (2x2), each wave 64x64 (4x4 frags of 16x16).
// OT: 0 = fp32 out, 1 = bf16 out.
template<int OT, bool RELU, bool RES>
__global__ __launch_bounds__(256) void k_gemm_bf(
    const unsigned short* __restrict__ A, const float* __restrict__ W,
    const float* __restrict__ bias, const float* __restrict__ R,
    void* __restrict__ Cout, int M, int N, int K) {
  __shared__ unsigned short As[128][40];
  __shared__ unsigned short Bs[128][40];
  int tid = threadIdx.x;
  int lane = tid & 63, wid = tid >> 6;
  int m0 = blockIdx.x * 128, n0 = blockIdx.y * 128;
  int wr = (wid >> 1) * 64, wc = (wid & 1) * 64;
  f32x4 acc[4][4] = {};

  int a_row = tid >> 1, a_koff = (tid & 1) * 16;
  int b_nb = tid & 31, b_kb = (tid >> 5) * 4;
  int lr = lane & 15, lq = lane >> 4;

  for (int k0 = 0; k0 < K; k0 += 32) {
    const unsigned short* ap = A + (size_t)(m0 + a_row) * K + k0 + a_koff;
    uint4 av0 = *(const uint4*)ap;
    uint4 av1 = *(const uint4*)(ap + 8);
    float wv[4][4];
    #pragma unroll
    for (int dk = 0; dk < 4; ++dk) {
      const float* wrow = W + (size_t)(k0 + b_kb + dk) * N + n0 + b_nb;
      #pragma unroll
      for (int j = 0; j < 4; ++j) wv[j][dk] = wrow[32 * j];
    }
    __syncthreads();
    *(uint4*)&As[a_row][a_koff]     = av0;
    *(uint4*)&As[a_row][a_koff + 8] = av1;
    #pragma unroll
    for (int j = 0; j < 4; ++j) {
      ushort4 pk;
      pk.x = f2bf(wv[j][0]); pk.y = f2bf(wv[j][1]);
      pk.z = f2bf(wv[j][2]); pk.w = f2bf(wv[j][3]);
      *(ushort4*)&Bs[b_nb + 32 * j][b_kb] = pk;
    }
    __syncthreads();
    short8 af[4], bf[4];
    #pragma unroll
    for (int m = 0; m < 4; ++m) af[m] = *(const short8*)&As[wr + m * 16 + lr][lq * 8];
    #pragma unroll
    for (int n = 0; n < 4; ++n) bf[n] = *(const short8*)&Bs[wc + n * 16 + lr][lq * 8];
    #pragma unroll
    for (int m = 0; m < 4; ++m)
      #pragma unroll
      for (int n = 0; n < 4; ++n)
        acc[m][n] = __builtin_amdgcn_mfma_f32_16x16x32_bf16(af[m], bf[n], acc[m][n], 0, 0, 0);
  }

  #pragma unroll
  for (int m = 0; m < 4; ++m) {
    #pragma unroll
    for (int n = 0; n < 4; ++n) {
      int col = n0 + wc + n * 16 + lr;
      float bv = bias ? bias[col] : 0.0f;
      #pragma unroll
      for (int i = 0; i < 4; ++i) {
        size_t row = (size_t)(m0 + wr + m * 16 + lq * 4 + i);
        float v = acc[m][n][i] + bv;
        if (RELU) v = fmaxf(v, 0.0f);
        if (RES)  v += R[row * N + col];
        if (OT == 0) ((float*)Cout)[row * N + col] = v;
        else ((unsigned short*)Cout)[row * N + col] = f2bf(v);
      }
    }
  }
}

// ---------------------------------------------------------------- flash attention (bf16 MFMA)
// Block = 4 waves, each wave 16 q-rows; 64-row Q tile per block, KV tiles of 64.
// Grid (T/64, B*H). Layout [B,T,E], head h at cols h*64..h*64+63.
__global__ __launch_bounds__(256) void k_fattn(
    const unsigned short* __restrict__ Q, const unsigned short* __restrict__ K,
    const unsigned short* __restrict__ V, unsigned short* __restrict__ O) {
  __shared__ unsigned short Ks[64][72];   // [k][d], 144B rows: 16B-aligned, ~2-way banks
  __shared__ unsigned short Vs[64][72];   // [d][k] (transposed at staging)
  __shared__ unsigned short Pl[4][16][72];// per-wave P transpose buffer
  int tid = threadIdx.x;
  int lane = tid & 63, wid = tid >> 6;
  int lr = lane & 15, lq = lane >> 4;
  int qt = blockIdx.x, bh = blockIdx.y;
  int b = bh >> 4, h = bh & 15;
  size_t base = ((size_t)b * T_) * E_ + h * HS_;
  int q0 = qt * 64 + wid * 16;

  // Q fragments in registers for the whole block (A-operand layout)
  short8 qf[2];
  #pragma unroll
  for (int s = 0; s < 2; ++s)
    qf[s] = *(const short8*)(Q + base + (size_t)(q0 + lr) * E_ + s * 32 + lq * 8);

  f32x4 o_acc[4] = {};
  float mrun[4], lrun[4];
  #pragma unroll
  for (int i = 0; i < 4; ++i) { mrun[i] = -1e30f; lrun[i] = 0.0f; }
  const float sc = 0.03125f * 1.44269504f;   // E^-0.5 folded with log2e
  int r = tid >> 2, cc = (tid & 3) * 16;

  for (int t = 0; t <= qt; ++t) {
    __syncthreads();                          // prev tile's reads done
    const unsigned short* kp = K + base + (size_t)(t * 64 + r) * E_ + cc;
    const unsigned short* vp = V + base + (size_t)(t * 64 + r) * E_ + cc;
    uint4 k0v = *(const uint4*)kp, k1v = *(const uint4*)(kp + 8);
    uint4 v0v = *(const uint4*)vp, v1v = *(const uint4*)(vp + 8);
    *(uint4*)&Ks[r][cc] = k0v;
    *(uint4*)&Ks[r][cc + 8] = k1v;
    unsigned short vtmp[16];
    *(uint4*)&vtmp[0] = v0v; *(uint4*)&vtmp[8] = v1v;
    #pragma unroll
    for (int j = 0; j < 16; ++j) Vs[cc + j][r] = vtmp[j];
    __syncthreads();                          // staging visible

    // S = Q K^T  (rows q, cols key)
    f32x4 sa[4] = {};
    #pragma unroll
    for (int nt = 0; nt < 4; ++nt)
      #pragma unroll
      for (int s = 0; s < 2; ++s) {
        short8 kf = *(const short8*)&Ks[nt * 16 + lr][s * 32 + lq * 8];
        sa[nt] = __builtin_amdgcn_mfma_f32_16x16x32_bf16(qf[s], kf, sa[nt], 0, 0, 0);
      }

    // mask + scale (log2 domain)
    float p[4][4];
    bool diag = (t == qt);
    #pragma unroll
    for (int nt = 0; nt < 4; ++nt)
      #pragma unroll
      for (int i = 0; i < 4; ++i) {
        float v = sa[nt][i] * sc;
        if (diag && (t * 64 + nt * 16 + lr > q0 + lq * 4 + i)) v = -1e30f;
        p[nt][i] = v;
      }
    // online softmax per q-row (row spread over 16 lanes lr)
    #pragma unroll
    for (int i = 0; i < 4; ++i) {
      float v = fmaxf(fmaxf(p[0][i], p[1][i]), fmaxf(p[2][i], p[3][i]));
      #pragma unroll
      for (int o = 1; o < 16; o <<= 1) v = fmaxf(v, __shfl_xor(v, o));
      float mn = fmaxf(mrun[i], v);
      float corr = __builtin_amdgcn_exp2f(mrun[i] - mn);
      mrun[i] = mn;
      float ps = 0.0f;
      #pragma unroll
      for (int nt = 0; nt < 4; ++nt) {
        float pe = __builtin_amdgcn_exp2f(p[nt][i] - mn);
        p[nt][i] = pe;
        ps += pe;
      }
      lrun[i] = lrun[i] * corr + ps;
      #pragma unroll
      for (int dn = 0; dn < 4; ++dn) o_acc[dn][i] *= corr;
    }
    // P -> LDS (transpose to A-fragment layout)
    #pragma unroll
    for (int nt = 0; nt < 4; ++nt)
      #pragma unroll
      for (int i = 0; i < 4; ++i)
        Pl[wid][lq * 4 + i][nt * 16 + lr] = f2bf(p[nt][i]);
    __syncthreads();                          // order P writes before P reads (safe)

    // O += P V   (cols = d, from transposed Vs)
    #pragma unroll
    for (int s = 0; s < 2; ++s) {
      short8 pa = *(const short8*)&Pl[wid][lr][s * 32 + lq * 8];
      #pragma unroll
      for (int dn = 0; dn < 4; ++dn) {
        short8 vf = *(const short8*)&Vs[dn * 16 + lr][s * 32 + lq * 8];
        o_acc[dn] = __builtin_amdgcn_mfma_f32_16x16x32_bf16(pa, vf, o_acc[dn], 0, 0, 0);
      }
    }
  }

  // normalize + write
  #pragma unroll
  for (int i = 0; i < 4; ++i) {
    float v = lrun[i];
    #pragma unroll
    for (int o = 1; o < 16; o <<= 1) v += __shfl_xor(v, o);
    lrun[i] = 1.0f / v;
  }
  #pragma unroll
  for (int dn = 0; dn < 4; ++dn)
    #pragma unroll
    for (int i = 0; i < 4; ++i) {
      size_t row = (size_t)(b * T_) + q0 + lq * 4 + i;
      O[row * E_ + h * HS_ + dn * 16 + lr] = f2bf(o_acc[dn][i] * lrun[i]);
    }
}

// ---------------------------------------------------------------- launch
extern "C" void kernel_launch(void* const* d_in, const int* in_sizes, int n_in,
                              void* d_out, int out_size, void* d_ws, size_t ws_size,
                              hipStream_t stream) {
  const int*   idx  = (const int*)d_in[0];
  const float* tok  = (const float*)d_in[1];
  const float* pos  = (const float*)d_in[2];
  const float* ln1g = (const float*)d_in[3];
  const float* ln1b = (const float*)d_in[4];
  const float* Wq   = (const float*)d_in[5];
  const float* Wk   = (const float*)d_in[6];
  const float* Wv   = (const float*)d_in[7];
  const float* Wo   = (const float*)d_in[8];
  const float* bo   = (const float*)d_in[9];
  const float* ln2g = (const float*)d_in[10];
  const float* ln2b = (const float*)d_in[11];
  const float* W1   = (const float*)d_in[12];
  const float* b1   = (const float*)d_in[13];
  const float* W2   = (const float*)d_in[14];
  const float* b2   = (const float*)d_in[15];
  const float* lnfg = (const float*)d_in[16];
  const float* lnfb = (const float*)d_in[17];
  const float* Wlm  = (const float*)d_in[18];
  const float* blm  = (const float*)d_in[19];

  // scratch: everything except hb lives in d_out (dead before final GEMM writes it)
  char* scr = (char*)d_out;
  const size_t MB = 1024 * 1024;
  float*          xf = (float*)(scr);                     // 16MB fp32 residual
  unsigned short* qb = (unsigned short*)(scr + 16 * MB);  // 8MB bf16
  unsigned short* kb = (unsigned short*)(scr + 24 * MB);  // 8MB
  unsigned short* vb = (unsigned short*)(scr + 32 * MB);  // 8MB
  unsigned short* ob = (unsigned short*)(scr + 40 * MB);  // 8MB
  unsigned short* mh = (unsigned short*)(scr + 48 * MB);  // 32MB
  unsigned short* hb = (unsigned short*)d_ws;             // 8MB (read during final GEMM)

  k_embed<<<M_, 256, 0, stream>>>(idx, tok, pos, xf);

  dim3 gE(M_ / 128, E_ / 128);
  dim3 gF(M_ / 128, 4 * E_ / 128);
  dim3 gV(M_ / 128, V_ / 128);

  for (int l = 0; l < L_; ++l) {
    size_t wOff  = (size_t)l * E_ * E_;
    size_t w1Off = (size_t)l * E_ * 4 * E_;
    k_ln_bf<<<M_, 256, 0, stream>>>(xf, ln1g + l * E_, ln1b + l * E_, hb);
    k_gemm_bf<1, false, false><<<gE, 256, 0, stream>>>(hb, Wq + wOff, nullptr, nullptr, qb, M_, E_, E_);
    k_gemm_bf<1, false, false><<<gE, 256, 0, stream>>>(hb, Wk + wOff, nullptr, nullptr, kb, M_, E_, E_);
    k_gemm_bf<1, false, false><<<gE, 256, 0, stream>>>(hb, Wv + wOff, nullptr, nullptr, vb, M_, E_, E_);
    k_fattn<<<dim3(T_ / 64, B_ * H_), 256, 0, stream>>>(qb, kb, vb, ob);
    k_gemm_bf<0, false, true><<<gE, 256, 0, stream>>>(ob, Wo + wOff, bo + l * E_, xf, xf, M_, E_, E_);
    k_ln_bf<<<M_, 256, 0, stream>>>(xf, ln2g + l * E_, ln2b + l * E_, hb);
    k_gemm_bf<1, true, false><<<gF, 256, 0, stream>>>(hb, W1 + w1Off, b1 + (size_t)l * 4 * E_, nullptr, mh, M_, 4 * E_, E_);
    k_gemm_bf<0, false, true><<<gE, 256, 0, stream>>>(mh, W2 + w1Off, b2 + l * E_, xf, xf, M_, E_, 4 * E_);
  }
  k_ln_bf<<<M_, 256, 0, stream>>>(xf, lnfg, lnfb, hb);
  k_gemm_bf<0, false, false><<<gV, 256, 0, stream>>>(hb, Wlm, blm, nullptr, (float*)d_out, M_, V_, E_);
}

// Round 4
// 3035.016 us; speedup vs baseline: 9.7585x; 1.4465x over previous
//
#include <hip/hip_runtime.h>
#include <math.h>

#define L_ 8
#define H_ 16
#define E_ 1024
#define V_ 32000
#define B_ 4
#define T_ 1024
#define HS_ 64
#define M_ 4096   // B*T
#define QKVS_ 3072  // fused qkv row stride

typedef __attribute__((ext_vector_type(8))) short short8;
typedef __attribute__((ext_vector_type(4))) float f32x4;

__device__ __forceinline__ unsigned short f2bf(float f) {
  unsigned int u = __builtin_bit_cast(unsigned int, f);
  u += 0x7fffu + ((u >> 16) & 1u);          // RNE
  return (unsigned short)(u >> 16);
}

// ---------------------------------------------------------------- embed (fp32 x)
__global__ __launch_bounds__(256) void k_embed(
    const int* __restrict__ idx, const float* __restrict__ tok,
    const float* __restrict__ pos, float* __restrict__ x) {
  int bt = blockIdx.x;
  int t  = bt & (T_ - 1);
  int token = idx[bt];
  const float4* te = (const float4*)(tok + (size_t)token * E_);
  const float4* pe = (const float4*)(pos + (size_t)t * E_);
  float4* xo = (float4*)(x + (size_t)bt * E_);
  int i = threadIdx.x;
  float4 a = te[i], b = pe[i];
  xo[i] = make_float4(a.x + b.x, a.y + b.y, a.z + b.z, a.w + b.w);
}

// ---------------------------------------------------------------- weight transpose+convert
// W[K][N] f32 -> WT[N][K] bf16, 64x64 tiles, blockIdx.z = matrix index (separate strides)
__global__ __launch_bounds__(256) void k_wt(
    const float* __restrict__ W, unsigned short* __restrict__ WT,
    int K, int N, size_t ss, size_t ds) {
  __shared__ unsigned short t[64][66];   // 132B rows -> bank stride 33, conflict-free
  const float* Ws = W + (size_t)blockIdx.z * ss;
  unsigned short* Wd = WT + (size_t)blockIdx.z * ds;
  int n0 = blockIdx.x * 64, k0 = blockIdx.y * 64;
  int tid = threadIdx.x;
  int c = tid & 63, r4 = tid >> 6;
  #pragma unroll
  for (int i = 0; i < 16; ++i) {
    int kr = i * 4 + r4;
    t[kr][c] = f2bf(Ws[(size_t)(k0 + kr) * N + n0 + c]);
  }
  __syncthreads();
  #pragma unroll
  for (int i = 0; i < 16; ++i) {
    int nr = i * 4 + r4;
    Wd[(size_t)(n0 + nr) * K + k0 + c] = t[c][nr];
  }
}

// ---------------------------------------------------------------- layernorm (fp32 in, bf16 out)
__device__ __forceinline__ float blk_sum256(float v, float* red) {
  #pragma unroll
  for (int o = 1; o < 64; o <<= 1) v += __shfl_xor(v, o);
  int wid = threadIdx.x >> 6, lane = threadIdx.x & 63;
  if (lane == 0) red[wid] = v;
  __syncthreads();
  v = red[0] + red[1] + red[2] + red[3];
  __syncthreads();
  return v;
}

__global__ __launch_bounds__(256) void k_ln_bf(
    const float* __restrict__ X, const float* __restrict__ g,
    const float* __restrict__ b, unsigned short* __restrict__ Y) {
  __shared__ float red[4];
  int row = blockIdx.x;
  int i = threadIdx.x;
  float4 xv = ((const float4*)(X + (size_t)row * E_))[i];
  float s = xv.x + xv.y + xv.z + xv.w;
  s = blk_sum256(s, red);
  float mean = s * (1.0f / E_);
  float dx = xv.x - mean, dy = xv.y - mean, dz = xv.z - mean, dw = xv.w - mean;
  float vs = dx*dx + dy*dy + dz*dz + dw*dw;
  vs = blk_sum256(vs, red);
  float rstd = rsqrtf(vs * (1.0f / E_) + 1e-5f);
  float4 gv = ((const float4*)g)[i];
  float4 bv = ((const float4*)b)[i];
  ushort4 o;
  o.x = f2bf(dx * rstd * gv.x + bv.x);
  o.y = f2bf(dy * rstd * gv.y + bv.y);
  o.z = f2bf(dz * rstd * gv.z + bv.z);
  o.w = f2bf(dw * rstd * gv.w + bv.w);
  ((ushort4*)(Y + (size_t)row * E_))[i] = o;
}

// ---------------------------------------------------------------- bf16 TN MFMA GEMM (m97 structure)
// C[M,N] = A[M,K](bf16) @ BT[N,K](bf16)^T (+bias)(+relu)(+res f32)
// 128xBN tile, BK=32, 256 threads = 4 waves (2x2); global_load_lds dwordx4 staging, linear LDS.
template<int BN, int OT, bool RELU, bool RES>
__global__ __launch_bounds__(256) void k_gemm_tn(
    const unsigned short* __restrict__ A, const unsigned short* __restrict__ BT,
    const float* __restrict__ bias, const float* __restrict__ R,
    void* __restrict__ Cout, int M, int N, int K) {
  constexpr int NF = BN / 32;                  // N-frags per wave
  __shared__ __attribute__((aligned(16))) unsigned short As[128 * 32];
  __shared__ __attribute__((aligned(16))) unsigned short Bs[BN * 32];
  int tid = threadIdx.x;
  int lane = tid & 63, w = tid >> 6;
  int lr = lane & 15, lq = lane >> 4;
  int m0 = blockIdx.x * 128, n0 = blockIdx.y * BN;
  int wr = (w >> 1) * 64, wc = (w & 1) * (BN / 2);

  // staging: lane l covers row w*16 + l/4, k-chunk (l&3)*8 (16B); LDS dest = wave base + lane*16
  int srow = w * 16 + (lane >> 2);
  int skoff = (lane & 3) * 8;
  const unsigned short* a0 = A + (size_t)(m0 + srow) * K + skoff;
  const unsigned short* b0 = BT + (size_t)(n0 + srow) * K + skoff;

  f32x4 acc[4][NF] = {};

  for (int k0 = 0; k0 < K; k0 += 32) {
    __syncthreads();
    __builtin_amdgcn_global_load_lds(
        (const __attribute__((address_space(1))) void*)(a0 + k0),
        (__attribute__((address_space(3))) void*)(As + w * 512), 16, 0, 0);
    __builtin_amdgcn_global_load_lds(
        (const __attribute__((address_space(1))) void*)(a0 + (size_t)64 * K + k0),
        (__attribute__((address_space(3))) void*)(As + 2048 + w * 512), 16, 0, 0);
    __builtin_amdgcn_global_load_lds(
        (const __attribute__((address_space(1))) void*)(b0 + k0),
        (__attribute__((address_space(3))) void*)(Bs + w * 512), 16, 0, 0);
    if constexpr (BN == 128)
      __builtin_amdgcn_global_load_lds(
          (const __attribute__((address_space(1))) void*)(b0 + (size_t)64 * K + k0),
          (__attribute__((address_space(3))) void*)(Bs + 2048 + w * 512), 16, 0, 0);
    __syncthreads();                           // vmcnt(0) drain + barrier
    short8 af[4], bf[NF];
    #pragma unroll
    for (int m = 0; m < 4; ++m) af[m] = *(const short8*)&As[(wr + m * 16 + lr) * 32 + lq * 8];
    #pragma unroll
    for (int n = 0; n < NF; ++n) bf[n] = *(const short8*)&Bs[(wc + n * 16 + lr) * 32 + lq * 8];
    #pragma unroll
    for (int m = 0; m < 4; ++m)
      #pragma unroll
      for (int n = 0; n < NF; ++n)
        acc[m][n] = __builtin_amdgcn_mfma_f32_16x16x32_bf16(af[m], bf[n], acc[m][n], 0, 0, 0);
  }

  #pragma unroll
  for (int m = 0; m < 4; ++m) {
    #pragma unroll
    for (int n = 0; n < NF; ++n) {
      int col = n0 + wc + n * 16 + lr;
      float bv = bias ? bias[col] : 0.0f;
      #pragma unroll
      for (int i = 0; i < 4; ++i) {
        size_t row = (size_t)(m0 + wr + m * 16 + lq * 4 + i);
        float v = acc[m][n][i] + bv;
        if (RELU) v = fmaxf(v, 0.0f);
        if (RES)  v += R[row * N + col];
        if (OT == 0) ((float*)Cout)[row * N + col] = v;
        else ((unsigned short*)Cout)[row * N + col] = f2bf(v);
      }
    }
  }
}

// ---------------------------------------------------------------- legacy GEMM (fp32 B) for LM fallback
template<int OT, bool RELU, bool RES>
__global__ __launch_bounds__(256) void k_gemm_bf(
    const unsigned short* __restrict__ A, const float* __restrict__ W,
    const float* __restrict__ bias, const float* __restrict__ R,
    void* __restrict__ Cout, int M, int N, int K) {
  __shared__ unsigned short As[128][40];
  __shared__ unsigned short Bs[128][40];
  int tid = threadIdx.x;
  int lane = tid & 63, wid = tid >> 6;
  int m0 = blockIdx.x * 128, n0 = blockIdx.y * 128;
  int wr = (wid >> 1) * 64, wc = (wid & 1) * 64;
  f32x4 acc[4][4] = {};
  int a_row = tid >> 1, a_koff = (tid & 1) * 16;
  int b_nb = tid & 31, b_kb = (tid >> 5) * 4;
  int lr = lane & 15, lq = lane >> 4;
  for (int k0 = 0; k0 < K; k0 += 32) {
    const unsigned short* ap = A + (size_t)(m0 + a_row) * K + k0 + a_koff;
    uint4 av0 = *(const uint4*)ap;
    uint4 av1 = *(const uint4*)(ap + 8);
    float wv[4][4];
    #pragma unroll
    for (int dk = 0; dk < 4; ++dk) {
      const float* wrow = W + (size_t)(k0 + b_kb + dk) * N + n0 + b_nb;
      #pragma unroll
      for (int j = 0; j < 4; ++j) wv[j][dk] = wrow[32 * j];
    }
    __syncthreads();
    *(uint4*)&As[a_row][a_koff]     = av0;
    *(uint4*)&As[a_row][a_koff + 8] = av1;
    #pragma unroll
    for (int j = 0; j < 4; ++j) {
      ushort4 pk;
      pk.x = f2bf(wv[j][0]); pk.y = f2bf(wv[j][1]);
      pk.z = f2bf(wv[j][2]); pk.w = f2bf(wv[j][3]);
      *(ushort4*)&Bs[b_nb + 32 * j][b_kb] = pk;
    }
    __syncthreads();
    short8 af[4], bf[4];
    #pragma unroll
    for (int m = 0; m < 4; ++m) af[m] = *(const short8*)&As[wr + m * 16 + lr][lq * 8];
    #pragma unroll
    for (int n = 0; n < 4; ++n) bf[n] = *(const short8*)&Bs[wc + n * 16 + lr][lq * 8];
    #pragma unroll
    for (int m = 0; m < 4; ++m)
      #pragma unroll
      for (int n = 0; n < 4; ++n)
        acc[m][n] = __builtin_amdgcn_mfma_f32_16x16x32_bf16(af[m], bf[n], acc[m][n], 0, 0, 0);
  }
  #pragma unroll
  for (int m = 0; m < 4; ++m) {
    #pragma unroll
    for (int n = 0; n < 4; ++n) {
      int col = n0 + wc + n * 16 + lr;
      float bv = bias ? bias[col] : 0.0f;
      #pragma unroll
      for (int i = 0; i < 4; ++i) {
        size_t row = (size_t)(m0 + wr + m * 16 + lq * 4 + i);
        float v = acc[m][n][i] + bv;
        if (RELU) v = fmaxf(v, 0.0f);
        if (RES)  v += R[row * N + col];
        if (OT == 0) ((float*)Cout)[row * N + col] = v;
        else ((unsigned short*)Cout)[row * N + col] = f2bf(v);
      }
    }
  }
}

// ---------------------------------------------------------------- flash attention (bf16 MFMA)
// Reads fused QKV buffer [M][3072]: q at +0, k at +1024, v at +2048 (head h at +h*64).
__global__ __launch_bounds__(256) void k_fattn(
    const unsigned short* __restrict__ QKV, unsigned short* __restrict__ O) {
  __shared__ unsigned short Ks[64][72];
  __shared__ unsigned short Vs[64][72];
  __shared__ unsigned short Pl[4][16][72];
  int tid = threadIdx.x;
  int lane = tid & 63, wid = tid >> 6;
  int lr = lane & 15, lq = lane >> 4;
  int qt = blockIdx.x, bh = blockIdx.y;
  int b = bh >> 4, h = bh & 15;
  size_t base = ((size_t)b * T_) * QKVS_ + h * HS_;
  int q0 = qt * 64 + wid * 16;

  short8 qf[2];
  #pragma unroll
  for (int s = 0; s < 2; ++s)
    qf[s] = *(const short8*)(QKV + base + (size_t)(q0 + lr) * QKVS_ + s * 32 + lq * 8);

  f32x4 o_acc[4] = {};
  float mrun[4], lrun[4];
  #pragma unroll
  for (int i = 0; i < 4; ++i) { mrun[i] = -1e30f; lrun[i] = 0.0f; }
  const float sc = 0.03125f * 1.44269504f;
  int r = tid >> 2, cc = (tid & 3) * 16;

  for (int t = 0; t <= qt; ++t) {
    __syncthreads();
    const unsigned short* kp = QKV + base + 1024 + (size_t)(t * 64 + r) * QKVS_ + cc;
    const unsigned short* vp = QKV + base + 2048 + (size_t)(t * 64 + r) * QKVS_ + cc;
    uint4 k0v = *(const uint4*)kp, k1v = *(const uint4*)(kp + 8);
    uint4 v0v = *(const uint4*)vp, v1v = *(const uint4*)(vp + 8);
    *(uint4*)&Ks[r][cc] = k0v;
    *(uint4*)&Ks[r][cc + 8] = k1v;
    unsigned short vtmp[16];
    *(uint4*)&vtmp[0] = v0v; *(uint4*)&vtmp[8] = v1v;
    #pragma unroll
    for (int j = 0; j < 16; ++j) Vs[cc + j][r] = vtmp[j];
    __syncthreads();

    f32x4 sa[4] = {};
    #pragma unroll
    for (int nt = 0; nt < 4; ++nt)
      #pragma unroll
      for (int s = 0; s < 2; ++s) {
        short8 kf = *(const short8*)&Ks[nt * 16 + lr][s * 32 + lq * 8];
        sa[nt] = __builtin_amdgcn_mfma_f32_16x16x32_bf16(qf[s], kf, sa[nt], 0, 0, 0);
      }

    float p[4][4];
    bool diag = (t == qt);
    #pragma unroll
    for (int nt = 0; nt < 4; ++nt)
      #pragma unroll
      for (int i = 0; i < 4; ++i) {
        float v = sa[nt][i] * sc;
        if (diag && (t * 64 + nt * 16 + lr > q0 + lq * 4 + i)) v = -1e30f;
        p[nt][i] = v;
      }
    #pragma unroll
    for (int i = 0; i < 4; ++i) {
      float v = fmaxf(fmaxf(p[0][i], p[1][i]), fmaxf(p[2][i], p[3][i]));
      #pragma unroll
      for (int o = 1; o < 16; o <<= 1) v = fmaxf(v, __shfl_xor(v, o));
      float mn = fmaxf(mrun[i], v);
      float corr = __builtin_amdgcn_exp2f(mrun[i] - mn);
      mrun[i] = mn;
      float ps = 0.0f;
      #pragma unroll
      for (int nt = 0; nt < 4; ++nt) {
        float pe = __builtin_amdgcn_exp2f(p[nt][i] - mn);
        p[nt][i] = pe;
        ps += pe;
      }
      lrun[i] = lrun[i] * corr + ps;
      #pragma unroll
      for (int dn = 0; dn < 4; ++dn) o_acc[dn][i] *= corr;
    }
    #pragma unroll
    for (int nt = 0; nt < 4; ++nt)
      #pragma unroll
      for (int i = 0; i < 4; ++i)
        Pl[wid][lq * 4 + i][nt * 16 + lr] = f2bf(p[nt][i]);
    __syncthreads();

    #pragma unroll
    for (int s = 0; s < 2; ++s) {
      short8 pa = *(const short8*)&Pl[wid][lr][s * 32 + lq * 8];
      #pragma unroll
      for (int dn = 0; dn < 4; ++dn) {
        short8 vf = *(const short8*)&Vs[dn * 16 + lr][s * 32 + lq * 8];
        o_acc[dn] = __builtin_amdgcn_mfma_f32_16x16x32_bf16(pa, vf, o_acc[dn], 0, 0, 0);
      }
    }
  }

  #pragma unroll
  for (int i = 0; i < 4; ++i) {
    float v = lrun[i];
    #pragma unroll
    for (int o = 1; o < 16; o <<= 1) v += __shfl_xor(v, o);
    lrun[i] = 1.0f / v;
  }
  #pragma unroll
  for (int dn = 0; dn < 4; ++dn)
    #pragma unroll
    for (int i = 0; i < 4; ++i) {
      size_t row = (size_t)(b * T_) + q0 + lq * 4 + i;
      O[row * E_ + h * HS_ + dn * 16 + lr] = f2bf(o_acc[dn][i] * lrun[i]);
    }
}

// ---------------------------------------------------------------- launch
extern "C" void kernel_launch(void* const* d_in, const int* in_sizes, int n_in,
                              void* d_out, int out_size, void* d_ws, size_t ws_size,
                              hipStream_t stream) {
  const int*   idx  = (const int*)d_in[0];
  const float* tok  = (const float*)d_in[1];
  const float* pos  = (const float*)d_in[2];
  const float* ln1g = (const float*)d_in[3];
  const float* ln1b = (const float*)d_in[4];
  const float* Wq   = (const float*)d_in[5];
  const float* Wk   = (const float*)d_in[6];
  const float* Wv   = (const float*)d_in[7];
  const float* Wo   = (const float*)d_in[8];
  const float* bo   = (const float*)d_in[9];
  const float* ln2g = (const float*)d_in[10];
  const float* ln2b = (const float*)d_in[11];
  const float* W1   = (const float*)d_in[12];
  const float* b1   = (const float*)d_in[13];
  const float* W2   = (const float*)d_in[14];
  const float* b2   = (const float*)d_in[15];
  const float* lnfg = (const float*)d_in[16];
  const float* lnfb = (const float*)d_in[17];
  const float* Wlm  = (const float*)d_in[18];
  const float* blm  = (const float*)d_in[19];

  char* scr = (char*)d_out;
  const size_t MB = 1024 * 1024;
  // d_out scratch (all dead before final GEMM writes d_out):
  float*          xf    = (float*)(scr);                      // 16MB fp32 residual
  unsigned short* qkvb  = (unsigned short*)(scr + 16 * MB);   // 24MB fused qkv bf16
  unsigned short* ob    = (unsigned short*)(scr + 40 * MB);   // 8MB
  unsigned short* mh    = (unsigned short*)(scr + 48 * MB);   // 32MB
  unsigned short* wqkvT = (unsigned short*)(scr + 80 * MB);   // 48MB [L][3072][1024]
  unsigned short* woT   = (unsigned short*)(scr + 128 * MB);  // 16MB [L][1024][1024]
  unsigned short* w1T   = (unsigned short*)(scr + 144 * MB);  // 64MB [L][4096][1024]
  unsigned short* w2T   = (unsigned short*)(scr + 208 * MB);  // 64MB [L][1024][4096]
  // d_ws: tensors read during the final (d_out-writing) GEMM
  unsigned short* hb    = (unsigned short*)d_ws;              // 8MB bf16 LN output
  unsigned short* wlmT  = (unsigned short*)((char*)d_ws + 8 * MB); // 65.5MB [32000][1024]
  const size_t EE = (size_t)E_ * E_;
  bool lm_fast = ws_size >= 8 * MB + (size_t)V_ * E_ * 2 + 1024;

  k_embed<<<M_, 256, 0, stream>>>(idx, tok, pos, xf);

  // weight conversion (every call; deterministic)
  k_wt<<<dim3(16, 16, L_), 256, 0, stream>>>(Wq, wqkvT,          E_, E_, EE, 3 * EE);
  k_wt<<<dim3(16, 16, L_), 256, 0, stream>>>(Wk, wqkvT + EE,     E_, E_, EE, 3 * EE);
  k_wt<<<dim3(16, 16, L_), 256, 0, stream>>>(Wv, wqkvT + 2 * EE, E_, E_, EE, 3 * EE);
  k_wt<<<dim3(16, 16, L_), 256, 0, stream>>>(Wo, woT,            E_, E_, EE, EE);
  k_wt<<<dim3(64, 16, L_), 256, 0, stream>>>(W1, w1T, E_, 4 * E_, 4 * EE, 4 * EE);
  k_wt<<<dim3(16, 64, L_), 256, 0, stream>>>(W2, w2T, 4 * E_, E_, 4 * EE, 4 * EE);
  if (lm_fast)
    k_wt<<<dim3(V_ / 64, 16, 1), 256, 0, stream>>>(Wlm, wlmT, E_, V_, 0, 0);

  for (int l = 0; l < L_; ++l) {
    k_ln_bf<<<M_, 256, 0, stream>>>(xf, ln1g + l * E_, ln1b + l * E_, hb);
    k_gemm_tn<128, 1, false, false><<<dim3(32, 24), 256, 0, stream>>>(
        hb, wqkvT + (size_t)l * 3 * EE, nullptr, nullptr, qkvb, M_, QKVS_, E_);
    k_fattn<<<dim3(T_ / 64, B_ * H_), 256, 0, stream>>>(qkvb, ob);
    k_gemm_tn<64, 0, false, true><<<dim3(32, 16), 256, 0, stream>>>(
        ob, woT + (size_t)l * EE, bo + l * E_, xf, xf, M_, E_, E_);
    k_ln_bf<<<M_, 256, 0, stream>>>(xf, ln2g + l * E_, ln2b + l * E_, hb);
    k_gemm_tn<128, 1, true, false><<<dim3(32, 32), 256, 0, stream>>>(
        hb, w1T + (size_t)l * 4 * EE, b1 + (size_t)l * 4 * E_, nullptr, mh, M_, 4 * E_, E_);
    k_gemm_tn<64, 0, false, true><<<dim3(32, 16), 256, 0, stream>>>(
        mh, w2T + (size_t)l * 4 * EE, b2 + l * E_, xf, xf, M_, E_, 4 * E_);
  }
  k_ln_bf<<<M_, 256, 0, stream>>>(xf, lnfg, lnfb, hb);
  if (lm_fast)
    k_gemm_tn<128, 0, false, false><<<dim3(32, V_ / 128), 256, 0, stream>>>(
        hb, wlmT, blm, nullptr, (float*)d_out, M_, V_, E_);
  else
    k_gemm_bf<0, false, false><<<dim3(32, V_ / 128), 256, 0, stream>>>(
        hb, Wlm, blm, nullptr, (float*)d_out, M_, V_, E_);
}

// Round 5
// 2706.345 us; speedup vs baseline: 10.9436x; 1.1214x over previous
//
#include <hip/hip_runtime.h>
#include <math.h>

#define L_ 8
#define H_ 16
#define E_ 1024
#define V_ 32000
#define B_ 4
#define T_ 1024
#define HS_ 64
#define M_ 4096   // B*T
#define QKVS_ 3072  // fused qkv row stride

typedef __attribute__((ext_vector_type(8))) short short8;
typedef __attribute__((ext_vector_type(4))) float f32x4;

__device__ __forceinline__ unsigned short f2bf(float f) {
  unsigned int u = __builtin_bit_cast(unsigned int, f);
  u += 0x7fffu + ((u >> 16) & 1u);          // RNE
  return (unsigned short)(u >> 16);
}

// ---------------------------------------------------------------- embed (fp32 x)
__global__ __launch_bounds__(256) void k_embed(
    const int* __restrict__ idx, const float* __restrict__ tok,
    const float* __restrict__ pos, float* __restrict__ x) {
  int bt = blockIdx.x;
  int t  = bt & (T_ - 1);
  int token = idx[bt];
  const float4* te = (const float4*)(tok + (size_t)token * E_);
  const float4* pe = (const float4*)(pos + (size_t)t * E_);
  float4* xo = (float4*)(x + (size_t)bt * E_);
  int i = threadIdx.x;
  float4 a = te[i], b = pe[i];
  xo[i] = make_float4(a.x + b.x, a.y + b.y, a.z + b.z, a.w + b.w);
}

// ---------------------------------------------------------------- weight transpose+convert
// W[K][N] f32 -> WT[N][K] bf16, 64x64 tiles, blockIdx.z = matrix index (separate strides)
__global__ __launch_bounds__(256) void k_wt(
    const float* __restrict__ W, unsigned short* __restrict__ WT,
    int K, int N, size_t ss, size_t ds) {
  __shared__ unsigned short t[64][66];   // stride 33 dwords -> conflict-free both sides
  const float* Ws = W + (size_t)blockIdx.z * ss;
  unsigned short* Wd = WT + (size_t)blockIdx.z * ds;
  int n0 = blockIdx.x * 64, k0 = blockIdx.y * 64;
  int tid = threadIdx.x;
  int c = tid & 63, r4 = tid >> 6;
  #pragma unroll
  for (int i = 0; i < 16; ++i) {
    int kr = i * 4 + r4;
    t[kr][c] = f2bf(Ws[(size_t)(k0 + kr) * N + n0 + c]);
  }
  __syncthreads();
  #pragma unroll
  for (int i = 0; i < 16; ++i) {
    int nr = i * 4 + r4;
    Wd[(size_t)(n0 + nr) * K + k0 + c] = t[c][nr];
  }
}

// ---------------------------------------------------------------- layernorm (fp32 in, bf16 out)
__device__ __forceinline__ float blk_sum256(float v, float* red) {
  #pragma unroll
  for (int o = 1; o < 64; o <<= 1) v += __shfl_xor(v, o);
  int wid = threadIdx.x >> 6, lane = threadIdx.x & 63;
  if (lane == 0) red[wid] = v;
  __syncthreads();
  v = red[0] + red[1] + red[2] + red[3];
  __syncthreads();
  return v;
}

__global__ __launch_bounds__(256) void k_ln_bf(
    const float* __restrict__ X, const float* __restrict__ g,
    const float* __restrict__ b, unsigned short* __restrict__ Y) {
  __shared__ float red[4];
  int row = blockIdx.x;
  int i = threadIdx.x;
  float4 xv = ((const float4*)(X + (size_t)row * E_))[i];
  float s = xv.x + xv.y + xv.z + xv.w;
  s = blk_sum256(s, red);
  float mean = s * (1.0f / E_);
  float dx = xv.x - mean, dy = xv.y - mean, dz = xv.z - mean, dw = xv.w - mean;
  float vs = dx*dx + dy*dy + dz*dz + dw*dw;
  vs = blk_sum256(vs, red);
  float rstd = rsqrtf(vs * (1.0f / E_) + 1e-5f);
  float4 gv = ((const float4*)g)[i];
  float4 bv = ((const float4*)b)[i];
  ushort4 o;
  o.x = f2bf(dx * rstd * gv.x + bv.x);
  o.y = f2bf(dy * rstd * gv.y + bv.y);
  o.z = f2bf(dz * rstd * gv.z + bv.z);
  o.w = f2bf(dw * rstd * gv.w + bv.w);
  ((ushort4*)(Y + (size_t)row * E_))[i] = o;
}

// ---------------------------------------------------------------- bf16 TN MFMA GEMM
// C[M,N] = A[M,K](bf16) @ BT[N,K](bf16)^T (+bias)(+relu)(+res f32)
// 128xBN tile, BK=64, 256 threads = 4 waves (2x2); global_load_lds dwordx4 staging.
// LDS XOR-swizzle on 16B chunks (c8 ^= row&7): linear gload dest + pre-swizzled
// global source + swizzled ds_read index (rule #21 both-sides pattern).
template<int BN, int OT, bool RELU, bool RES>
__global__ __launch_bounds__(256) void k_gemm_tn(
    const unsigned short* __restrict__ A, const unsigned short* __restrict__ BT,
    const float* __restrict__ bias, const float* __restrict__ R,
    void* __restrict__ Cout, int M, int N, int K) {
  constexpr int NF = BN / 32;                  // N-frags per wave
  __shared__ __attribute__((aligned(16))) unsigned short As[128 * 64];
  __shared__ __attribute__((aligned(16))) unsigned short Bs[BN * 64];
  int tid = threadIdx.x;
  int lane = tid & 63, w = tid >> 6;
  int lr = lane & 15, lq = lane >> 4;
  int m0 = blockIdx.x * 128, n0 = blockIdx.y * BN;
  int wr = (w >> 1) * 64, wc = (w & 1) * (BN / 2);

  // staging: chunk C = j*256 + w*64 + lane -> LDS bytes C*16 (linear).
  // row = C>>3 (row&7 == lane>>3), dest c8 = lane&7; source c8 = (lane&7)^(lane>>3).
  int srow = w * 8 + (lane >> 3);
  int skoff = ((lane & 7) ^ (lane >> 3)) * 8;
  const unsigned short* a0 = A + (size_t)(m0 + srow) * K + skoff;
  const unsigned short* b0 = BT + (size_t)(n0 + srow) * K + skoff;

  f32x4 acc[4][NF] = {};

  for (int k0 = 0; k0 < K; k0 += 64) {
    __syncthreads();
    #pragma unroll
    for (int j = 0; j < 4; ++j)
      __builtin_amdgcn_global_load_lds(
          (const __attribute__((address_space(1))) void*)(a0 + (size_t)(j * 32) * K + k0),
          (__attribute__((address_space(3))) void*)(As + j * 2048 + w * 512), 16, 0, 0);
    #pragma unroll
    for (int j = 0; j < NF; ++j)
      __builtin_amdgcn_global_load_lds(
          (const __attribute__((address_space(1))) void*)(b0 + (size_t)(j * 32) * K + k0),
          (__attribute__((address_space(3))) void*)(Bs + j * 2048 + w * 512), 16, 0, 0);
    __syncthreads();                           // vmcnt(0) drain + barrier
    short8 af[4][2], bf[NF][2];
    #pragma unroll
    for (int m = 0; m < 4; ++m)
      #pragma unroll
      for (int ks = 0; ks < 2; ++ks)
        af[m][ks] = *(const short8*)&As[(wr + m * 16 + lr) * 64 + (((ks * 4 + lq) ^ (lr & 7)) << 3)];
    #pragma unroll
    for (int n = 0; n < NF; ++n)
      #pragma unroll
      for (int ks = 0; ks < 2; ++ks)
        bf[n][ks] = *(const short8*)&Bs[(wc + n * 16 + lr) * 64 + (((ks * 4 + lq) ^ (lr & 7)) << 3)];
    #pragma unroll
    for (int ks = 0; ks < 2; ++ks)
      #pragma unroll
      for (int m = 0; m < 4; ++m)
        #pragma unroll
        for (int n = 0; n < NF; ++n)
          acc[m][n] = __builtin_amdgcn_mfma_f32_16x16x32_bf16(af[m][ks], bf[n][ks], acc[m][n], 0, 0, 0);
  }

  #pragma unroll
  for (int m = 0; m < 4; ++m) {
    #pragma unroll
    for (int n = 0; n < NF; ++n) {
      int col = n0 + wc + n * 16 + lr;
      float bv = bias ? bias[col] : 0.0f;
      #pragma unroll
      for (int i = 0; i < 4; ++i) {
        size_t row = (size_t)(m0 + wr + m * 16 + lq * 4 + i);
        float v = acc[m][n][i] + bv;
        if (RELU) v = fmaxf(v, 0.0f);
        if (RES)  v += R[row * N + col];
        if (OT == 0) ((float*)Cout)[row * N + col] = v;
        else ((unsigned short*)Cout)[row * N + col] = f2bf(v);
      }
    }
  }
}

// ---------------------------------------------------------------- legacy GEMM (fp32 B) for LM fallback
template<int OT, bool RELU, bool RES>
__global__ __launch_bounds__(256) void k_gemm_bf(
    const unsigned short* __restrict__ A, const float* __restrict__ W,
    const float* __restrict__ bias, const float* __restrict__ R,
    void* __restrict__ Cout, int M, int N, int K) {
  __shared__ unsigned short As[128][40];
  __shared__ unsigned short Bs[128][40];
  int tid = threadIdx.x;
  int lane = tid & 63, wid = tid >> 6;
  int m0 = blockIdx.x * 128, n0 = blockIdx.y * 128;
  int wr = (wid >> 1) * 64, wc = (wid & 1) * 64;
  f32x4 acc[4][4] = {};
  int a_row = tid >> 1, a_koff = (tid & 1) * 16;
  int b_nb = tid & 31, b_kb = (tid >> 5) * 4;
  int lr = lane & 15, lq = lane >> 4;
  for (int k0 = 0; k0 < K; k0 += 32) {
    const unsigned short* ap = A + (size_t)(m0 + a_row) * K + k0 + a_koff;
    uint4 av0 = *(const uint4*)ap;
    uint4 av1 = *(const uint4*)(ap + 8);
    float wv[4][4];
    #pragma unroll
    for (int dk = 0; dk < 4; ++dk) {
      const float* wrow = W + (size_t)(k0 + b_kb + dk) * N + n0 + b_nb;
      #pragma unroll
      for (int j = 0; j < 4; ++j) wv[j][dk] = wrow[32 * j];
    }
    __syncthreads();
    *(uint4*)&As[a_row][a_koff]     = av0;
    *(uint4*)&As[a_row][a_koff + 8] = av1;
    #pragma unroll
    for (int j = 0; j < 4; ++j) {
      ushort4 pk;
      pk.x = f2bf(wv[j][0]); pk.y = f2bf(wv[j][1]);
      pk.z = f2bf(wv[j][2]); pk.w = f2bf(wv[j][3]);
      *(ushort4*)&Bs[b_nb + 32 * j][b_kb] = pk;
    }
    __syncthreads();
    short8 af[4], bf[4];
    #pragma unroll
    for (int m = 0; m < 4; ++m) af[m] = *(const short8*)&As[wr + m * 16 + lr][lq * 8];
    #pragma unroll
    for (int n = 0; n < 4; ++n) bf[n] = *(const short8*)&Bs[wc + n * 16 + lr][lq * 8];
    #pragma unroll
    for (int m = 0; m < 4; ++m)
      #pragma unroll
      for (int n = 0; n < 4; ++n)
        acc[m][n] = __builtin_amdgcn_mfma_f32_16x16x32_bf16(af[m], bf[n], acc[m][n], 0, 0, 0);
  }
  #pragma unroll
  for (int m = 0; m < 4; ++m) {
    #pragma unroll
    for (int n = 0; n < 4; ++n) {
      int col = n0 + wc + n * 16 + lr;
      float bv = bias ? bias[col] : 0.0f;
      #pragma unroll
      for (int i = 0; i < 4; ++i) {
        size_t row = (size_t)(m0 + wr + m * 16 + lq * 4 + i);
        float v = acc[m][n][i] + bv;
        if (RELU) v = fmaxf(v, 0.0f);
        if (RES)  v += R[row * N + col];
        if (OT == 0) ((float*)Cout)[row * N + col] = v;
        else ((unsigned short*)Cout)[row * N + col] = f2bf(v);
      }
    }
  }
}

// ---------------------------------------------------------------- flash attention (bf16 MFMA)
// 4 waves x 32 q-rows = 128-row Q tile per block; KV tiles of 64.
// Grid (T/128, B*H). Reads fused QKV [M][3072]: q+0, k+1024, v+2048 (head h at +h*64).
__global__ __launch_bounds__(256) void k_fattn(
    const unsigned short* __restrict__ QKV, unsigned short* __restrict__ O) {
  __shared__ unsigned short Ks[64][72];
  __shared__ unsigned short Vs[64][74];    // [d][k] transposed; 74-pad: 4-way write, free read
  __shared__ unsigned short Pl[4][32][72];
  int tid = threadIdx.x;
  int lane = tid & 63, wid = tid >> 6;
  int lr = lane & 15, lq = lane >> 4;
  int qt = blockIdx.x, bh = blockIdx.y;
  int b = bh >> 4, h = bh & 15;
  size_t base = ((size_t)b * T_) * QKVS_ + h * HS_;
  int q0w = qt * 128 + wid * 32;

  short8 qf[2][2];
  #pragma unroll
  for (int g = 0; g < 2; ++g)
    #pragma unroll
    for (int s = 0; s < 2; ++s)
      qf[g][s] = *(const short8*)(QKV + base + (size_t)(q0w + g * 16 + lr) * QKVS_ + s * 32 + lq * 8);

  f32x4 o_acc[2][4] = {};
  float mrun[2][4], lrun[2][4];
  #pragma unroll
  for (int g = 0; g < 2; ++g)
    #pragma unroll
    for (int i = 0; i < 4; ++i) { mrun[g][i] = -1e30f; lrun[g][i] = 0.0f; }
  const float sc = 0.03125f * 1.44269504f;   // E^-0.5 folded with log2e
  int r = tid >> 2, cc = (tid & 3) * 16;
  int ntiles = 2 * qt + 2;

  for (int t = 0; t < ntiles; ++t) {
    __syncthreads();
    const unsigned short* kp = QKV + base + 1024 + (size_t)(t * 64 + r) * QKVS_ + cc;
    const unsigned short* vp = kp + 1024;
    uint4 k0v = *(const uint4*)kp, k1v = *(const uint4*)(kp + 8);
    uint4 v0v = *(const uint4*)vp, v1v = *(const uint4*)(vp + 8);
    *(uint4*)&Ks[r][cc] = k0v;
    *(uint4*)&Ks[r][cc + 8] = k1v;
    unsigned short vt[16];
    *(uint4*)&vt[0] = v0v; *(uint4*)&vt[8] = v1v;
    #pragma unroll
    for (int j = 0; j < 16; ++j) Vs[cc + j][r] = vt[j];
    __syncthreads();

    // S = Q K^T, both row groups share each K fragment
    f32x4 sa[2][4] = {};
    #pragma unroll
    for (int nt = 0; nt < 4; ++nt)
      #pragma unroll
      for (int s = 0; s < 2; ++s) {
        short8 kf = *(const short8*)&Ks[nt * 16 + lr][s * 32 + lq * 8];
        sa[0][nt] = __builtin_amdgcn_mfma_f32_16x16x32_bf16(qf[0][s], kf, sa[0][nt], 0, 0, 0);
        sa[1][nt] = __builtin_amdgcn_mfma_f32_16x16x32_bf16(qf[1][s], kf, sa[1][nt], 0, 0, 0);
      }

    bool diag = (t >= 2 * qt);
    float p[2][4][4];
    #pragma unroll
    for (int g = 0; g < 2; ++g)
      #pragma unroll
      for (int nt = 0; nt < 4; ++nt)
        #pragma unroll
        for (int i = 0; i < 4; ++i) {
          float v = sa[g][nt][i] * sc;
          if (diag && (t * 64 + nt * 16 + lr > q0w + g * 16 + lq * 4 + i)) v = -1e30f;
          p[g][nt][i] = v;
        }
    #pragma unroll
    for (int g = 0; g < 2; ++g)
      #pragma unroll
      for (int i = 0; i < 4; ++i) {
        float v = fmaxf(fmaxf(p[g][0][i], p[g][1][i]), fmaxf(p[g][2][i], p[g][3][i]));
        #pragma unroll
        for (int o = 1; o < 16; o <<= 1) v = fmaxf(v, __shfl_xor(v, o));
        float mn = fmaxf(mrun[g][i], v);
        float corr = __builtin_amdgcn_exp2f(mrun[g][i] - mn);
        mrun[g][i] = mn;
        float ps = 0.0f;
        #pragma unroll
        for (int nt = 0; nt < 4; ++nt) {
          float pe = __builtin_amdgcn_exp2f(p[g][nt][i] - mn);
          p[g][nt][i] = pe;
          ps += pe;
        }
        lrun[g][i] = lrun[g][i] * corr + ps;
        #pragma unroll
        for (int dn = 0; dn < 4; ++dn) o_acc[g][dn][i] *= corr;
      }
    #pragma unroll
    for (int g = 0; g < 2; ++g)
      #pragma unroll
      for (int nt = 0; nt < 4; ++nt)
        #pragma unroll
        for (int i = 0; i < 4; ++i)
          Pl[wid][g * 16 + lq * 4 + i][nt * 16 + lr] = f2bf(p[g][nt][i]);
    __syncthreads();                          // order P writes before P reads

    #pragma unroll
    for (int s = 0; s < 2; ++s) {
      short8 pa0 = *(const short8*)&Pl[wid][lr][s * 32 + lq * 8];
      short8 pa1 = *(const short8*)&Pl[wid][16 + lr][s * 32 + lq * 8];
      #pragma unroll
      for (int dn = 0; dn < 4; ++dn) {
        short8 vf = *(const short8*)&Vs[dn * 16 + lr][s * 32 + lq * 8];
        o_acc[0][dn] = __builtin_amdgcn_mfma_f32_16x16x32_bf16(pa0, vf, o_acc[0][dn], 0, 0, 0);
        o_acc[1][dn] = __builtin_amdgcn_mfma_f32_16x16x32_bf16(pa1, vf, o_acc[1][dn], 0, 0, 0);
      }
    }
  }

  #pragma unroll
  for (int g = 0; g < 2; ++g)
    #pragma unroll
    for (int i = 0; i < 4; ++i) {
      float v = lrun[g][i];
      #pragma unroll
      for (int o = 1; o < 16; o <<= 1) v += __shfl_xor(v, o);
      lrun[g][i] = 1.0f / v;
    }
  #pragma unroll
  for (int g = 0; g < 2; ++g)
    #pragma unroll
    for (int dn = 0; dn < 4; ++dn)
      #pragma unroll
      for (int i = 0; i < 4; ++i) {
        size_t row = (size_t)(b * T_) + q0w + g * 16 + lq * 4 + i;
        O[row * E_ + h * HS_ + dn * 16 + lr] = f2bf(o_acc[g][dn][i] * lrun[g][i]);
      }
}

// ---------------------------------------------------------------- launch
extern "C" void kernel_launch(void* const* d_in, const int* in_sizes, int n_in,
                              void* d_out, int out_size, void* d_ws, size_t ws_size,
                              hipStream_t stream) {
  const int*   idx  = (const int*)d_in[0];
  const float* tok  = (const float*)d_in[1];
  const float* pos  = (const float*)d_in[2];
  const float* ln1g = (const float*)d_in[3];
  const float* ln1b = (const float*)d_in[4];
  const float* Wq   = (const float*)d_in[5];
  const float* Wk   = (const float*)d_in[6];
  const float* Wv   = (const float*)d_in[7];
  const float* Wo   = (const float*)d_in[8];
  const float* bo   = (const float*)d_in[9];
  const float* ln2g = (const float*)d_in[10];
  const float* ln2b = (const float*)d_in[11];
  const float* W1   = (const float*)d_in[12];
  const float* b1   = (const float*)d_in[13];
  const float* W2   = (const float*)d_in[14];
  const float* b2   = (const float*)d_in[15];
  const float* lnfg = (const float*)d_in[16];
  const float* lnfb = (const float*)d_in[17];
  const float* Wlm  = (const float*)d_in[18];
  const float* blm  = (const float*)d_in[19];

  char* scr = (char*)d_out;
  const size_t MB = 1024 * 1024;
  // d_out scratch (all dead before final GEMM writes d_out):
  float*          xf    = (float*)(scr);                      // 16MB fp32 residual
  unsigned short* qkvb  = (unsigned short*)(scr + 16 * MB);   // 24MB fused qkv bf16
  unsigned short* ob    = (unsigned short*)(scr + 40 * MB);   // 8MB
  unsigned short* mh    = (unsigned short*)(scr + 48 * MB);   // 32MB
  unsigned short* wqkvT = (unsigned short*)(scr + 80 * MB);   // 48MB [L][3072][1024]
  unsigned short* woT   = (unsigned short*)(scr + 128 * MB);  // 16MB [L][1024][1024]
  unsigned short* w1T   = (unsigned short*)(scr + 144 * MB);  // 64MB [L][4096][1024]
  unsigned short* w2T   = (unsigned short*)(scr + 208 * MB);  // 64MB [L][1024][4096]
  // d_ws: tensors read during the final (d_out-writing) GEMM
  unsigned short* hb    = (unsigned short*)d_ws;              // 8MB bf16 LN output
  unsigned short* wlmT  = (unsigned short*)((char*)d_ws + 8 * MB); // 65.5MB [32000][1024]
  const size_t EE = (size_t)E_ * E_;
  bool lm_fast = ws_size >= 8 * MB + (size_t)V_ * E_ * 2 + 1024;

  k_embed<<<M_, 256, 0, stream>>>(idx, tok, pos, xf);

  // weight conversion (every call; deterministic)
  k_wt<<<dim3(16, 16, L_), 256, 0, stream>>>(Wq, wqkvT,          E_, E_, EE, 3 * EE);
  k_wt<<<dim3(16, 16, L_), 256, 0, stream>>>(Wk, wqkvT + EE,     E_, E_, EE, 3 * EE);
  k_wt<<<dim3(16, 16, L_), 256, 0, stream>>>(Wv, wqkvT + 2 * EE, E_, E_, EE, 3 * EE);
  k_wt<<<dim3(16, 16, L_), 256, 0, stream>>>(Wo, woT,            E_, E_, EE, EE);
  k_wt<<<dim3(64, 16, L_), 256, 0, stream>>>(W1, w1T, E_, 4 * E_, 4 * EE, 4 * EE);
  k_wt<<<dim3(16, 64, L_), 256, 0, stream>>>(W2, w2T, 4 * E_, E_, 4 * EE, 4 * EE);
  if (lm_fast)
    k_wt<<<dim3(V_ / 64, 16, 1), 256, 0, stream>>>(Wlm, wlmT, E_, V_, 0, 0);

  for (int l = 0; l < L_; ++l) {
    k_ln_bf<<<M_, 256, 0, stream>>>(xf, ln1g + l * E_, ln1b + l * E_, hb);
    k_gemm_tn<128, 1, false, false><<<dim3(32, 24), 256, 0, stream>>>(
        hb, wqkvT + (size_t)l * 3 * EE, nullptr, nullptr, qkvb, M_, QKVS_, E_);
    k_fattn<<<dim3(T_ / 128, B_ * H_), 256, 0, stream>>>(qkvb, ob);
    k_gemm_tn<64, 0, false, true><<<dim3(32, 16), 256, 0, stream>>>(
        ob, woT + (size_t)l * EE, bo + l * E_, xf, xf, M_, E_, E_);
    k_ln_bf<<<M_, 256, 0, stream>>>(xf, ln2g + l * E_, ln2b + l * E_, hb);
    k_gemm_tn<128, 1, true, false><<<dim3(32, 32), 256, 0, stream>>>(
        hb, w1T + (size_t)l * 4 * EE, b1 + (size_t)l * 4 * E_, nullptr, mh, M_, 4 * E_, E_);
    k_gemm_tn<64, 0, false, true><<<dim3(32, 16), 256, 0, stream>>>(
        mh, w2T + (size_t)l * 4 * EE, b2 + l * E_, xf, xf, M_, E_, 4 * E_);
  }
  k_ln_bf<<<M_, 256, 0, stream>>>(xf, lnfg, lnfb, hb);
  if (lm_fast)
    k_gemm_tn<128, 0, false, false><<<dim3(32, V_ / 128), 256, 0, stream>>>(
        hb, wlmT, blm, nullptr, (float*)d_out, M_, V_, E_);
  else
    k_gemm_bf<0, false, false><<<dim3(32, V_ / 128), 256, 0, stream>>>(
        hb, Wlm, blm, nullptr, (float*)d_out, M_, V_, E_);
}

// Round 6
// 2644.128 us; speedup vs baseline: 11.2011x; 1.0235x over previous
//
#include <hip/hip_runtime.h>
#include <math.h>

#define L_ 8
#define H_ 16
#define E_ 1024
#define V_ 32000
#define B_ 4
#define T_ 1024
#define HS_ 64
#define M_ 4096   // B*T
#define QKVS_ 3072  // fused qkv row stride

typedef __attribute__((ext_vector_type(8))) short short8;
typedef __attribute__((ext_vector_type(4))) float f32x4;

__device__ __forceinline__ unsigned short f2bf(float f) {
  unsigned int u = __builtin_bit_cast(unsigned int, f);
  u += 0x7fffu + ((u >> 16) & 1u);          // RNE
  return (unsigned short)(u >> 16);
}

// ---------------------------------------------------------------- embed (fp32 x)
__global__ __launch_bounds__(256) void k_embed(
    const int* __restrict__ idx, const float* __restrict__ tok,
    const float* __restrict__ pos, float* __restrict__ x) {
  int bt = blockIdx.x;
  int t  = bt & (T_ - 1);
  int token = idx[bt];
  const float4* te = (const float4*)(tok + (size_t)token * E_);
  const float4* pe = (const float4*)(pos + (size_t)t * E_);
  float4* xo = (float4*)(x + (size_t)bt * E_);
  int i = threadIdx.x;
  float4 a = te[i], b = pe[i];
  xo[i] = make_float4(a.x + b.x, a.y + b.y, a.z + b.z, a.w + b.w);
}

// ---------------------------------------------------------------- weight transpose+convert
__global__ __launch_bounds__(256) void k_wt(
    const float* __restrict__ W, unsigned short* __restrict__ WT,
    int K, int N, size_t ss, size_t ds) {
  __shared__ unsigned short t[64][66];
  const float* Ws = W + (size_t)blockIdx.z * ss;
  unsigned short* Wd = WT + (size_t)blockIdx.z * ds;
  int n0 = blockIdx.x * 64, k0 = blockIdx.y * 64;
  int tid = threadIdx.x;
  int c = tid & 63, r4 = tid >> 6;
  #pragma unroll
  for (int i = 0; i < 16; ++i) {
    int kr = i * 4 + r4;
    t[kr][c] = f2bf(Ws[(size_t)(k0 + kr) * N + n0 + c]);
  }
  __syncthreads();
  #pragma unroll
  for (int i = 0; i < 16; ++i) {
    int nr = i * 4 + r4;
    Wd[(size_t)(n0 + nr) * K + k0 + c] = t[c][nr];
  }
}

// ---------------------------------------------------------------- layernorm (fp32 in, bf16 out)
__device__ __forceinline__ float blk_sum256(float v, float* red) {
  #pragma unroll
  for (int o = 1; o < 64; o <<= 1) v += __shfl_xor(v, o);
  int wid = threadIdx.x >> 6, lane = threadIdx.x & 63;
  if (lane == 0) red[wid] = v;
  __syncthreads();
  v = red[0] + red[1] + red[2] + red[3];
  __syncthreads();
  return v;
}

__global__ __launch_bounds__(256) void k_ln_bf(
    const float* __restrict__ X, const float* __restrict__ g,
    const float* __restrict__ b, unsigned short* __restrict__ Y) {
  __shared__ float red[4];
  int row = blockIdx.x;
  int i = threadIdx.x;
  float4 xv = ((const float4*)(X + (size_t)row * E_))[i];
  float s = xv.x + xv.y + xv.z + xv.w;
  s = blk_sum256(s, red);
  float mean = s * (1.0f / E_);
  float dx = xv.x - mean, dy = xv.y - mean, dz = xv.z - mean, dw = xv.w - mean;
  float vs = dx*dx + dy*dy + dz*dz + dw*dw;
  vs = blk_sum256(vs, red);
  float rstd = rsqrtf(vs * (1.0f / E_) + 1e-5f);
  float4 gv = ((const float4*)g)[i];
  float4 bv = ((const float4*)b)[i];
  ushort4 o;
  o.x = f2bf(dx * rstd * gv.x + bv.x);
  o.y = f2bf(dy * rstd * gv.y + bv.y);
  o.z = f2bf(dz * rstd * gv.z + bv.z);
  o.w = f2bf(dw * rstd * gv.w + bv.w);
  ((ushort4*)(Y + (size_t)row * E_))[i] = o;
}

// ---------------------------------------------------------------- 256x256 8-phase bf16 GEMM
// C[4096,N] = A[4096,K] @ BT[N,K]^T (+bias)(+relu). 512 thr = 8 waves (2M x 4N).
// BK=64, double-buffered 128KB LDS, 16B-chunk XOR swizzle (both sides),
// raw s_barrier + counted vmcnt(2) once per K-tile (T3+T4), setprio around MFMA (T5).
#define BUFE 16384   // 256*64 elements per buffer per matrix

#define GLDS(src, dst) __builtin_amdgcn_global_load_lds( \
    (const __attribute__((address_space(1))) void*)(src), \
    (__attribute__((address_space(3))) void*)(dst), 16, 0, 0)

#define BAR() do { asm volatile("" ::: "memory"); __builtin_amdgcn_s_barrier(); \
                   asm volatile("" ::: "memory"); } while (0)

template<int OT, bool RELU>
__global__ __launch_bounds__(512, 2) void k_gemm_256(
    const unsigned short* __restrict__ A, const unsigned short* __restrict__ BT,
    const float* __restrict__ bias, void* __restrict__ Cout, int N, int K) {
  __shared__ __attribute__((aligned(16))) unsigned short As[2 * BUFE];  // 64KB
  __shared__ __attribute__((aligned(16))) unsigned short Bs[2 * BUFE];  // 64KB
  int tid = threadIdx.x;
  int lane = tid & 63, w = tid >> 6;           // 8 waves
  int lr = lane & 15, lq = (lane >> 4) & 3;
  int wm = w >> 2, wn = w & 3;                 // 2 x 4 wave grid

  // bijective XCD swizzle (m204), m-fastest decompose (M/256 = 16 blocks)
  int nwg = gridDim.x, orig = blockIdx.x;
  int qq = nwg >> 3, rr = nwg & 7;
  int xcd = orig & 7, lid = orig >> 3;
  int wg = (xcd < rr ? xcd * (qq + 1) : rr * (qq + 1) + (xcd - rr) * qq) + lid;
  int m0 = (wg & 15) * 256;
  int n0 = (wg >> 4) * 256;

  // staging source: chunk swizzle c8_src = (lane&7) ^ (lane>>3); dest linear
  int srow = w * 8 + (lane >> 3);
  int skoff = ((lane & 7) ^ (lane >> 3)) * 8;
  const unsigned short* aS = A + (size_t)(m0 + srow) * K + skoff;
  const unsigned short* bS = BT + (size_t)(n0 + srow) * K + skoff;

#define STG_A(boff, half, tt) { \
  GLDS(aS + (size_t)((half) * 128) * K + (tt) * 64,        &As[(boff) + (((half) * 128) << 6) + (w << 9)]); \
  GLDS(aS + (size_t)((half) * 128 + 64) * K + (tt) * 64,   &As[(boff) + (((half) * 128 + 64) << 6) + (w << 9)]); }
#define STG_B(boff, half, tt) { \
  GLDS(bS + (size_t)((half) * 128) * K + (tt) * 64,        &Bs[(boff) + (((half) * 128) << 6) + (w << 9)]); \
  GLDS(bS + (size_t)((half) * 128 + 64) * K + (tt) * 64,   &Bs[(boff) + (((half) * 128 + 64) << 6) + (w << 9)]); }
#define LDA_(dst, mh, ks) { _Pragma("unroll") for (int m_ = 0; m_ < 4; ++m_) \
  dst[m_] = *(const short8*)&As[so + ((wm * 128 + (mh) * 64 + m_ * 16 + lr) << 6) + ((((ks) * 4 + lq) ^ (lr & 7)) << 3)]; }
#define LDB_(dst, ks) { _Pragma("unroll") for (int n_ = 0; n_ < 4; ++n_) \
  dst[n_] = *(const short8*)&Bs[so + ((wn * 64 + n_ * 16 + lr) << 6) + ((((ks) * 4 + lq) ^ (lr & 7)) << 3)]; }
#define MMA(afr, mofs) do { __builtin_amdgcn_s_setprio(1); \
  _Pragma("unroll") for (int m_ = 0; m_ < 4; ++m_) { \
    _Pragma("unroll") for (int n_ = 0; n_ < 4; ++n_) \
      acc[(mofs) + m_][n_] = __builtin_amdgcn_mfma_f32_16x16x32_bf16(afr[m_], bfr[n_], acc[(mofs) + m_][n_], 0, 0, 0); } \
  __builtin_amdgcn_s_setprio(0); } while (0)

  f32x4 acc[8][4] = {};
  const int NT = K >> 6;

  // prologue: stage tile 0 fully + B0(1); wait for tile 0 only
  STG_A(0, 0, 0); STG_A(0, 1, 0); STG_B(0, 0, 0); STG_B(0, 1, 0);
  if (NT > 1) {
    STG_B(BUFE, 0, 1);
    asm volatile("s_waitcnt vmcnt(2)" ::: "memory");
  } else {
    asm volatile("s_waitcnt vmcnt(0)" ::: "memory");
  }
  BAR();

  for (int t = 0; t < NT; ++t) {
    const int so = (t & 1) * BUFE;
    const int nbuf = ((t + 1) & 1) * BUFE;
    short8 af0[4], af1[4], bfr[4];
    // ---- P0: af_lo ks0 + B ks0 ; stage B1(t+1) -> idle buf
    LDA_(af0, 0, 0);
    LDB_(bfr, 0);
    if (t + 1 < NT) { STG_B(nbuf, 1, t + 1); }
    BAR();
    MMA(af0, 0);
    BAR();
    // ---- P1: af_hi ks0 ; stage A0(t+1) -> idle buf
    LDA_(af1, 1, 0);
    if (t + 1 < NT) { STG_A(nbuf, 0, t + 1); }
    BAR();
    MMA(af1, 4);
    BAR();
    // ---- P2: af_lo ks1 + B ks1 ; stage A1(t+1) -> idle buf
    LDA_(af0, 0, 1);
    LDB_(bfr, 1);
    if (t + 1 < NT) { STG_A(nbuf, 1, t + 1); }
    BAR();
    MMA(af0, 0);
    BAR();
    // ---- P3: af_hi ks1 ; stage B0(t+2) -> current buf B region (dead after P2 barrier)
    LDA_(af1, 1, 1);
    if (t + 2 < NT) { STG_B(so, 0, t + 2); }
    BAR();
    MMA(af1, 4);
    if (t + 2 < NT) { asm volatile("s_waitcnt vmcnt(2)" ::: "memory"); }
    else            { asm volatile("s_waitcnt vmcnt(0)" ::: "memory"); }
    BAR();
  }

  #pragma unroll
  for (int m = 0; m < 8; ++m) {
    #pragma unroll
    for (int n = 0; n < 4; ++n) {
      int col = n0 + wn * 64 + n * 16 + lr;
      float bv = bias ? bias[col] : 0.0f;
      #pragma unroll
      for (int i = 0; i < 4; ++i) {
        size_t row = (size_t)(m0 + wm * 128 + m * 16 + lq * 4 + i);
        float v = acc[m][n][i] + bv;
        if (RELU) v = fmaxf(v, 0.0f);
        if (OT == 0) ((float*)Cout)[row * N + col] = v;
        else ((unsigned short*)Cout)[row * N + col] = f2bf(v);
      }
    }
  }
#undef STG_A
#undef STG_B
#undef LDA_
#undef LDB_
#undef MMA
}

// ---------------------------------------------------------------- bf16 TN MFMA GEMM (2-phase, BN<=128)
template<int BN, int OT, bool RELU, bool RES>
__global__ __launch_bounds__(256) void k_gemm_tn(
    const unsigned short* __restrict__ A, const unsigned short* __restrict__ BT,
    const float* __restrict__ bias, const float* __restrict__ R,
    void* __restrict__ Cout, int M, int N, int K) {
  constexpr int NF = BN / 32;
  __shared__ __attribute__((aligned(16))) unsigned short As[128 * 64];
  __shared__ __attribute__((aligned(16))) unsigned short Bs[BN * 64];
  int tid = threadIdx.x;
  int lane = tid & 63, w = tid >> 6;
  int lr = lane & 15, lq = lane >> 4;
  int m0 = blockIdx.x * 128, n0 = blockIdx.y * BN;
  int wr = (w >> 1) * 64, wc = (w & 1) * (BN / 2);

  int srow = w * 8 + (lane >> 3);
  int skoff = ((lane & 7) ^ (lane >> 3)) * 8;
  const unsigned short* a0 = A + (size_t)(m0 + srow) * K + skoff;
  const unsigned short* b0 = BT + (size_t)(n0 + srow) * K + skoff;

  f32x4 acc[4][NF] = {};

  for (int k0 = 0; k0 < K; k0 += 64) {
    __syncthreads();
    #pragma unroll
    for (int j = 0; j < 4; ++j)
      __builtin_amdgcn_global_load_lds(
          (const __attribute__((address_space(1))) void*)(a0 + (size_t)(j * 32) * K + k0),
          (__attribute__((address_space(3))) void*)(As + j * 2048 + w * 512), 16, 0, 0);
    #pragma unroll
    for (int j = 0; j < NF; ++j)
      __builtin_amdgcn_global_load_lds(
          (const __attribute__((address_space(1))) void*)(b0 + (size_t)(j * 32) * K + k0),
          (__attribute__((address_space(3))) void*)(Bs + j * 2048 + w * 512), 16, 0, 0);
    __syncthreads();
    short8 af[4][2], bf[NF][2];
    #pragma unroll
    for (int m = 0; m < 4; ++m)
      #pragma unroll
      for (int ks = 0; ks < 2; ++ks)
        af[m][ks] = *(const short8*)&As[(wr + m * 16 + lr) * 64 + (((ks * 4 + lq) ^ (lr & 7)) << 3)];
    #pragma unroll
    for (int n = 0; n < NF; ++n)
      #pragma unroll
      for (int ks = 0; ks < 2; ++ks)
        bf[n][ks] = *(const short8*)&Bs[(wc + n * 16 + lr) * 64 + (((ks * 4 + lq) ^ (lr & 7)) << 3)];
    #pragma unroll
    for (int ks = 0; ks < 2; ++ks)
      #pragma unroll
      for (int m = 0; m < 4; ++m)
        #pragma unroll
        for (int n = 0; n < NF; ++n)
          acc[m][n] = __builtin_amdgcn_mfma_f32_16x16x32_bf16(af[m][ks], bf[n][ks], acc[m][n], 0, 0, 0);
  }

  #pragma unroll
  for (int m = 0; m < 4; ++m) {
    #pragma unroll
    for (int n = 0; n < NF; ++n) {
      int col = n0 + wc + n * 16 + lr;
      float bv = bias ? bias[col] : 0.0f;
      #pragma unroll
      for (int i = 0; i < 4; ++i) {
        size_t row = (size_t)(m0 + wr + m * 16 + lq * 4 + i);
        float v = acc[m][n][i] + bv;
        if (RELU) v = fmaxf(v, 0.0f);
        if (RES)  v += R[row * N + col];
        if (OT == 0) ((float*)Cout)[row * N + col] = v;
        else ((unsigned short*)Cout)[row * N + col] = f2bf(v);
      }
    }
  }
}

// ---------------------------------------------------------------- legacy GEMM (fp32 B) for LM fallback
template<int OT, bool RELU, bool RES>
__global__ __launch_bounds__(256) void k_gemm_bf(
    const unsigned short* __restrict__ A, const float* __restrict__ W,
    const float* __restrict__ bias, const float* __restrict__ R,
    void* __restrict__ Cout, int M, int N, int K) {
  __shared__ unsigned short As[128][40];
  __shared__ unsigned short Bs[128][40];
  int tid = threadIdx.x;
  int lane = tid & 63, wid = tid >> 6;
  int m0 = blockIdx.x * 128, n0 = blockIdx.y * 128;
  int wr = (wid >> 1) * 64, wc = (wid & 1) * 64;
  f32x4 acc[4][4] = {};
  int a_row = tid >> 1, a_koff = (tid & 1) * 16;
  int b_nb = tid & 31, b_kb = (tid >> 5) * 4;
  int lr = lane & 15, lq = lane >> 4;
  for (int k0 = 0; k0 < K; k0 += 32) {
    const unsigned short* ap = A + (size_t)(m0 + a_row) * K + k0 + a_koff;
    uint4 av0 = *(const uint4*)ap;
    uint4 av1 = *(const uint4*)(ap + 8);
    float wv[4][4];
    #pragma unroll
    for (int dk = 0; dk < 4; ++dk) {
      const float* wrow = W + (size_t)(k0 + b_kb + dk) * N + n0 + b_nb;
      #pragma unroll
      for (int j = 0; j < 4; ++j) wv[j][dk] = wrow[32 * j];
    }
    __syncthreads();
    *(uint4*)&As[a_row][a_koff]     = av0;
    *(uint4*)&As[a_row][a_koff + 8] = av1;
    #pragma unroll
    for (int j = 0; j < 4; ++j) {
      ushort4 pk;
      pk.x = f2bf(wv[j][0]); pk.y = f2bf(wv[j][1]);
      pk.z = f2bf(wv[j][2]); pk.w = f2bf(wv[j][3]);
      *(ushort4*)&Bs[b_nb + 32 * j][b_kb] = pk;
    }
    __syncthreads();
    short8 af[4], bf[4];
    #pragma unroll
    for (int m = 0; m < 4; ++m) af[m] = *(const short8*)&As[wr + m * 16 + lr][lq * 8];
    #pragma unroll
    for (int n = 0; n < 4; ++n) bf[n] = *(const short8*)&Bs[wc + n * 16 + lr][lq * 8];
    #pragma unroll
    for (int m = 0; m < 4; ++m)
      #pragma unroll
      for (int n = 0; n < 4; ++n)
        acc[m][n] = __builtin_amdgcn_mfma_f32_16x16x32_bf16(af[m], bf[n], acc[m][n], 0, 0, 0);
  }
  #pragma unroll
  for (int m = 0; m < 4; ++m) {
    #pragma unroll
    for (int n = 0; n < 4; ++n) {
      int col = n0 + wc + n * 16 + lr;
      float bv = bias ? bias[col] : 0.0f;
      #pragma unroll
      for (int i = 0; i < 4; ++i) {
        size_t row = (size_t)(m0 + wr + m * 16 + lq * 4 + i);
        float v = acc[m][n][i] + bv;
        if (RELU) v = fmaxf(v, 0.0f);
        if (RES)  v += R[row * N + col];
        if (OT == 0) ((float*)Cout)[row * N + col] = v;
        else ((unsigned short*)Cout)[row * N + col] = f2bf(v);
      }
    }
  }
}

// ---------------------------------------------------------------- flash attention (bf16 MFMA)
__global__ __launch_bounds__(256) void k_fattn(
    const unsigned short* __restrict__ QKV, unsigned short* __restrict__ O) {
  __shared__ unsigned short Ks[64][72];
  __shared__ unsigned short Vs[64][74];
  __shared__ unsigned short Pl[4][32][72];
  int tid = threadIdx.x;
  int lane = tid & 63, wid = tid >> 6;
  int lr = lane & 15, lq = lane >> 4;
  int qt = blockIdx.x, bh = blockIdx.y;
  int b = bh >> 4, h = bh & 15;
  size_t base = ((size_t)b * T_) * QKVS_ + h * HS_;
  int q0w = qt * 128 + wid * 32;

  short8 qf[2][2];
  #pragma unroll
  for (int g = 0; g < 2; ++g)
    #pragma unroll
    for (int s = 0; s < 2; ++s)
      qf[g][s] = *(const short8*)(QKV + base + (size_t)(q0w + g * 16 + lr) * QKVS_ + s * 32 + lq * 8);

  f32x4 o_acc[2][4] = {};
  float mrun[2][4], lrun[2][4];
  #pragma unroll
  for (int g = 0; g < 2; ++g)
    #pragma unroll
    for (int i = 0; i < 4; ++i) { mrun[g][i] = -1e30f; lrun[g][i] = 0.0f; }
  const float sc = 0.03125f * 1.44269504f;
  int r = tid >> 2, cc = (tid & 3) * 16;
  int ntiles = 2 * qt + 2;

  for (int t = 0; t < ntiles; ++t) {
    __syncthreads();
    const unsigned short* kp = QKV + base + 1024 + (size_t)(t * 64 + r) * QKVS_ + cc;
    const unsigned short* vp = kp + 1024;
    uint4 k0v = *(const uint4*)kp, k1v = *(const uint4*)(kp + 8);
    uint4 v0v = *(const uint4*)vp, v1v = *(const uint4*)(vp + 8);
    *(uint4*)&Ks[r][cc] = k0v;
    *(uint4*)&Ks[r][cc + 8] = k1v;
    unsigned short vt[16];
    *(uint4*)&vt[0] = v0v; *(uint4*)&vt[8] = v1v;
    #pragma unroll
    for (int j = 0; j < 16; ++j) Vs[cc + j][r] = vt[j];
    __syncthreads();

    f32x4 sa[2][4] = {};
    #pragma unroll
    for (int nt = 0; nt < 4; ++nt)
      #pragma unroll
      for (int s = 0; s < 2; ++s) {
        short8 kf = *(const short8*)&Ks[nt * 16 + lr][s * 32 + lq * 8];
        sa[0][nt] = __builtin_amdgcn_mfma_f32_16x16x32_bf16(qf[0][s], kf, sa[0][nt], 0, 0, 0);
        sa[1][nt] = __builtin_amdgcn_mfma_f32_16x16x32_bf16(qf[1][s], kf, sa[1][nt], 0, 0, 0);
      }

    bool diag = (t >= 2 * qt);
    float p[2][4][4];
    #pragma unroll
    for (int g = 0; g < 2; ++g)
      #pragma unroll
      for (int nt = 0; nt < 4; ++nt)
        #pragma unroll
        for (int i = 0; i < 4; ++i) {
          float v = sa[g][nt][i] * sc;
          if (diag && (t * 64 + nt * 16 + lr > q0w + g * 16 + lq * 4 + i)) v = -1e30f;
          p[g][nt][i] = v;
        }
    #pragma unroll
    for (int g = 0; g < 2; ++g)
      #pragma unroll
      for (int i = 0; i < 4; ++i) {
        float v = fmaxf(fmaxf(p[g][0][i], p[g][1][i]), fmaxf(p[g][2][i], p[g][3][i]));
        #pragma unroll
        for (int o = 1; o < 16; o <<= 1) v = fmaxf(v, __shfl_xor(v, o));
        float mn = fmaxf(mrun[g][i], v);
        float corr = __builtin_amdgcn_exp2f(mrun[g][i] - mn);
        mrun[g][i] = mn;
        float ps = 0.0f;
        #pragma unroll
        for (int nt = 0; nt < 4; ++nt) {
          float pe = __builtin_amdgcn_exp2f(p[g][nt][i] - mn);
          p[g][nt][i] = pe;
          ps += pe;
        }
        lrun[g][i] = lrun[g][i] * corr + ps;
        #pragma unroll
        for (int dn = 0; dn < 4; ++dn) o_acc[g][dn][i] *= corr;
      }
    #pragma unroll
    for (int g = 0; g < 2; ++g)
      #pragma unroll
      for (int nt = 0; nt < 4; ++nt)
        #pragma unroll
        for (int i = 0; i < 4; ++i)
          Pl[wid][g * 16 + lq * 4 + i][nt * 16 + lr] = f2bf(p[g][nt][i]);
    __syncthreads();

    #pragma unroll
    for (int s = 0; s < 2; ++s) {
      short8 pa0 = *(const short8*)&Pl[wid][lr][s * 32 + lq * 8];
      short8 pa1 = *(const short8*)&Pl[wid][16 + lr][s * 32 + lq * 8];
      #pragma unroll
      for (int dn = 0; dn < 4; ++dn) {
        short8 vf = *(const short8*)&Vs[dn * 16 + lr][s * 32 + lq * 8];
        o_acc[0][dn] = __builtin_amdgcn_mfma_f32_16x16x32_bf16(pa0, vf, o_acc[0][dn], 0, 0, 0);
        o_acc[1][dn] = __builtin_amdgcn_mfma_f32_16x16x32_bf16(pa1, vf, o_acc[1][dn], 0, 0, 0);
      }
    }
  }

  #pragma unroll
  for (int g = 0; g < 2; ++g)
    #pragma unroll
    for (int i = 0; i < 4; ++i) {
      float v = lrun[g][i];
      #pragma unroll
      for (int o = 1; o < 16; o <<= 1) v += __shfl_xor(v, o);
      lrun[g][i] = 1.0f / v;
    }
  #pragma unroll
  for (int g = 0; g < 2; ++g)
    #pragma unroll
    for (int dn = 0; dn < 4; ++dn)
      #pragma unroll
      for (int i = 0; i < 4; ++i) {
        size_t row = (size_t)(b * T_) + q0w + g * 16 + lq * 4 + i;
        O[row * E_ + h * HS_ + dn * 16 + lr] = f2bf(o_acc[g][dn][i] * lrun[g][i]);
      }
}

// ---------------------------------------------------------------- launch
extern "C" void kernel_launch(void* const* d_in, const int* in_sizes, int n_in,
                              void* d_out, int out_size, void* d_ws, size_t ws_size,
                              hipStream_t stream) {
  const int*   idx  = (const int*)d_in[0];
  const float* tok  = (const float*)d_in[1];
  const float* pos  = (const float*)d_in[2];
  const float* ln1g = (const float*)d_in[3];
  const float* ln1b = (const float*)d_in[4];
  const float* Wq   = (const float*)d_in[5];
  const float* Wk   = (const float*)d_in[6];
  const float* Wv   = (const float*)d_in[7];
  const float* Wo   = (const float*)d_in[8];
  const float* bo   = (const float*)d_in[9];
  const float* ln2g = (const float*)d_in[10];
  const float* ln2b = (const float*)d_in[11];
  const float* W1   = (const float*)d_in[12];
  const float* b1   = (const float*)d_in[13];
  const float* W2   = (const float*)d_in[14];
  const float* b2   = (const float*)d_in[15];
  const float* lnfg = (const float*)d_in[16];
  const float* lnfb = (const float*)d_in[17];
  const float* Wlm  = (const float*)d_in[18];
  const float* blm  = (const float*)d_in[19];

  char* scr = (char*)d_out;
  const size_t MB = 1024 * 1024;
  float*          xf    = (float*)(scr);
  unsigned short* qkvb  = (unsigned short*)(scr + 16 * MB);
  unsigned short* ob    = (unsigned short*)(scr + 40 * MB);
  unsigned short* mh    = (unsigned short*)(scr + 48 * MB);
  unsigned short* wqkvT = (unsigned short*)(scr + 80 * MB);
  unsigned short* woT   = (unsigned short*)(scr + 128 * MB);
  unsigned short* w1T   = (unsigned short*)(scr + 144 * MB);
  unsigned short* w2T   = (unsigned short*)(scr + 208 * MB);
  unsigned short* hb    = (unsigned short*)d_ws;
  unsigned short* wlmT  = (unsigned short*)((char*)d_ws + 8 * MB);
  const size_t EE = (size_t)E_ * E_;
  bool lm_fast = ws_size >= 8 * MB + (size_t)V_ * E_ * 2 + 1024;

  k_embed<<<M_, 256, 0, stream>>>(idx, tok, pos, xf);

  k_wt<<<dim3(16, 16, L_), 256, 0, stream>>>(Wq, wqkvT,          E_, E_, EE, 3 * EE);
  k_wt<<<dim3(16, 16, L_), 256, 0, stream>>>(Wk, wqkvT + EE,     E_, E_, EE, 3 * EE);
  k_wt<<<dim3(16, 16, L_), 256, 0, stream>>>(Wv, wqkvT + 2 * EE, E_, E_, EE, 3 * EE);
  k_wt<<<dim3(16, 16, L_), 256, 0, stream>>>(Wo, woT,            E_, E_, EE, EE);
  k_wt<<<dim3(64, 16, L_), 256, 0, stream>>>(W1, w1T, E_, 4 * E_, 4 * EE, 4 * EE);
  k_wt<<<dim3(16, 64, L_), 256, 0, stream>>>(W2, w2T, 4 * E_, E_, 4 * EE, 4 * EE);
  if (lm_fast)
    k_wt<<<dim3(V_ / 64, 16, 1), 256, 0, stream>>>(Wlm, wlmT, E_, V_, 0, 0);

  for (int l = 0; l < L_; ++l) {
    k_ln_bf<<<M_, 256, 0, stream>>>(xf, ln1g + l * E_, ln1b + l * E_, hb);
    k_gemm_256<1, false><<<16 * (QKVS_ / 256), 512, 0, stream>>>(
        hb, wqkvT + (size_t)l * 3 * EE, nullptr, qkvb, QKVS_, E_);
    k_fattn<<<dim3(T_ / 128, B_ * H_), 256, 0, stream>>>(qkvb, ob);
    k_gemm_tn<64, 0, false, true><<<dim3(32, 16), 256, 0, stream>>>(
        ob, woT + (size_t)l * EE, bo + l * E_, xf, xf, M_, E_, E_);
    k_ln_bf<<<M_, 256, 0, stream>>>(xf, ln2g + l * E_, ln2b + l * E_, hb);
    k_gemm_256<1, true><<<16 * (4 * E_ / 256), 512, 0, stream>>>(
        hb, w1T + (size_t)l * 4 * EE, b1 + (size_t)l * 4 * E_, mh, 4 * E_, E_);
    k_gemm_tn<64, 0, false, true><<<dim3(32, 16), 256, 0, stream>>>(
        mh, w2T + (size_t)l * 4 * EE, b2 + l * E_, xf, xf, M_, E_, 4 * E_);
  }
  k_ln_bf<<<M_, 256, 0, stream>>>(xf, lnfg, lnfb, hb);
  if (lm_fast)
    k_gemm_256<0, false><<<16 * (V_ / 256), 512, 0, stream>>>(
        hb, wlmT, blm, (float*)d_out, V_, E_);
  else
    k_gemm_bf<0, false, false><<<dim3(32, V_ / 128), 256, 0, stream>>>(
        hb, Wlm, blm, nullptr, (float*)d_out, M_, V_, E_);
}

// Round 7
// 2545.799 us; speedup vs baseline: 11.6337x; 1.0386x over previous
//
#include <hip/hip_runtime.h>
#include <math.h>

#define L_ 8
#define H_ 16
#define E_ 1024
#define V_ 32000
#define B_ 4
#define T_ 1024
#define HS_ 64
#define M_ 4096   // B*T
#define QKVS_ 3072  // fused qkv row stride

typedef __attribute__((ext_vector_type(8))) short short8;
typedef __attribute__((ext_vector_type(4))) float f32x4;

__device__ __forceinline__ unsigned short f2bf(float f) {
  unsigned int u = __builtin_bit_cast(unsigned int, f);
  u += 0x7fffu + ((u >> 16) & 1u);          // RNE
  return (unsigned short)(u >> 16);
}

// ---------------------------------------------------------------- embed (fp32 x)
__global__ __launch_bounds__(256) void k_embed(
    const int* __restrict__ idx, const float* __restrict__ tok,
    const float* __restrict__ pos, float* __restrict__ x) {
  int bt = blockIdx.x;
  int t  = bt & (T_ - 1);
  int token = idx[bt];
  const float4* te = (const float4*)(tok + (size_t)token * E_);
  const float4* pe = (const float4*)(pos + (size_t)t * E_);
  float4* xo = (float4*)(x + (size_t)bt * E_);
  int i = threadIdx.x;
  float4 a = te[i], b = pe[i];
  xo[i] = make_float4(a.x + b.x, a.y + b.y, a.z + b.z, a.w + b.w);
}

// ---------------------------------------------------------------- weight transpose+convert
__global__ __launch_bounds__(256) void k_wt(
    const float* __restrict__ W, unsigned short* __restrict__ WT,
    int K, int N, size_t ss, size_t ds) {
  __shared__ unsigned short t[64][66];
  const float* Ws = W + (size_t)blockIdx.z * ss;
  unsigned short* Wd = WT + (size_t)blockIdx.z * ds;
  int n0 = blockIdx.x * 64, k0 = blockIdx.y * 64;
  int tid = threadIdx.x;
  int c = tid & 63, r4 = tid >> 6;
  #pragma unroll
  for (int i = 0; i < 16; ++i) {
    int kr = i * 4 + r4;
    t[kr][c] = f2bf(Ws[(size_t)(k0 + kr) * N + n0 + c]);
  }
  __syncthreads();
  #pragma unroll
  for (int i = 0; i < 16; ++i) {
    int nr = i * 4 + r4;
    Wd[(size_t)(n0 + nr) * K + k0 + c] = t[c][nr];
  }
}

// ---------------------------------------------------------------- layernorm (fp32 in, bf16 out)
__device__ __forceinline__ float blk_sum256(float v, float* red) {
  #pragma unroll
  for (int o = 1; o < 64; o <<= 1) v += __shfl_xor(v, o);
  int wid = threadIdx.x >> 6, lane = threadIdx.x & 63;
  if (lane == 0) red[wid] = v;
  __syncthreads();
  v = red[0] + red[1] + red[2] + red[3];
  __syncthreads();
  return v;
}

__global__ __launch_bounds__(256) void k_ln_bf(
    const float* __restrict__ X, const float* __restrict__ g,
    const float* __restrict__ b, unsigned short* __restrict__ Y) {
  __shared__ float red[4];
  int row = blockIdx.x;
  int i = threadIdx.x;
  float4 xv = ((const float4*)(X + (size_t)row * E_))[i];
  float s = xv.x + xv.y + xv.z + xv.w;
  s = blk_sum256(s, red);
  float mean = s * (1.0f / E_);
  float dx = xv.x - mean, dy = xv.y - mean, dz = xv.z - mean, dw = xv.w - mean;
  float vs = dx*dx + dy*dy + dz*dz + dw*dw;
  vs = blk_sum256(vs, red);
  float rstd = rsqrtf(vs * (1.0f / E_) + 1e-5f);
  float4 gv = ((const float4*)g)[i];
  float4 bv = ((const float4*)b)[i];
  ushort4 o;
  o.x = f2bf(dx * rstd * gv.x + bv.x);
  o.y = f2bf(dy * rstd * gv.y + bv.y);
  o.z = f2bf(dz * rstd * gv.z + bv.z);
  o.w = f2bf(dw * rstd * gv.w + bv.w);
  ((ushort4*)(Y + (size_t)row * E_))[i] = o;
}

// ---------------------------------------------------------------- split-K reduce (+bias +residual into xf)
__global__ __launch_bounds__(256) void k_red4(
    const float* __restrict__ p, const float* __restrict__ bias,
    float* __restrict__ xf) {
  const int ME = M_ * E_;
  int i = blockIdx.x * 1024 + threadIdx.x * 4;
  float4 a = *(const float4*)(p + i);
  float4 b = *(const float4*)(p + ME + i);
  float4 c = *(const float4*)(p + 2 * ME + i);
  float4 d = *(const float4*)(p + 3 * ME + i);
  float4 bv = *(const float4*)(bias + (i & (E_ - 1)));
  float4 x = *(float4*)(xf + i);
  x.x += a.x + b.x + c.x + d.x + bv.x;
  x.y += a.y + b.y + c.y + d.y + bv.y;
  x.z += a.z + b.z + c.z + d.z + bv.z;
  x.w += a.w + b.w + c.w + d.w + bv.w;
  *(float4*)(xf + i) = x;
}

// ---------------------------------------------------------------- 256x256 8-phase bf16 GEMM
// C[4096,N] = A[4096,K] @ BT[N,K]^T (+bias)(+relu). 512 thr = 8 waves (2M x 4N).
// BK=64, double-buffered 128KB LDS, 16B-chunk XOR swizzle (both sides),
// raw s_barrier + counted vmcnt(2) once per K-tile, setprio around MFMA.
// DEC: 0 = m-fastest (16 m-blocks), 1 = n-fastest (LM head), 2 = split-K=4 partials.
#define BUFE 16384   // 256*64 elements per buffer per matrix

#define GLDS(src, dst) __builtin_amdgcn_global_load_lds( \
    (const __attribute__((address_space(1))) void*)(src), \
    (__attribute__((address_space(3))) void*)(dst), 16, 0, 0)

#define BAR() do { asm volatile("" ::: "memory"); __builtin_amdgcn_s_barrier(); \
                   asm volatile("" ::: "memory"); } while (0)

template<int OT, bool RELU, int DEC>
__global__ __launch_bounds__(512, 2) void k_gemm_256(
    const unsigned short* __restrict__ A, const unsigned short* __restrict__ BT,
    const float* __restrict__ bias, void* __restrict__ Cout, int N, int K, int Kstr) {
  __shared__ __attribute__((aligned(16))) unsigned short As[2 * BUFE];  // 64KB
  __shared__ __attribute__((aligned(16))) unsigned short Bs[2 * BUFE];  // 64KB
  int tid = threadIdx.x;
  int lane = tid & 63, w = tid >> 6;           // 8 waves
  int lr = lane & 15, lq = (lane >> 4) & 3;
  int wm = w >> 2, wn = w & 3;                 // 2 x 4 wave grid

  // bijective XCD swizzle (m204)
  int nwg = gridDim.x, orig = blockIdx.x;
  int qq = nwg >> 3, rr = nwg & 7;
  int xcd = orig & 7, lid = orig >> 3;
  int wg = (xcd < rr ? xcd * (qq + 1) : rr * (qq + 1) + (xcd - rr) * qq) + lid;
  int m0, n0, kofs = 0;
  size_t cofs = 0;
  if constexpr (DEC == 0) { m0 = (wg & 15) * 256; n0 = (wg >> 4) * 256; }
  else if constexpr (DEC == 1) { int nbn = N >> 8; m0 = (wg / nbn) * 256; n0 = (wg % nbn) * 256; }
  else {
    int inner = wg & 63;
    m0 = (inner & 15) * 256; n0 = (inner >> 4) * 256;
    int ks = wg >> 6;
    kofs = ks * K;
    cofs = (size_t)ks * M_ * (size_t)N;
  }

  // staging source: chunk swizzle c8_src = (lane&7) ^ (lane>>3); dest linear
  int srow = w * 8 + (lane >> 3);
  int skoff = ((lane & 7) ^ (lane >> 3)) * 8;
  const unsigned short* aS = A + (size_t)(m0 + srow) * Kstr + kofs + skoff;
  const unsigned short* bS = BT + (size_t)(n0 + srow) * Kstr + kofs + skoff;

#define STG_A(boff, half, tt) { \
  GLDS(aS + (size_t)((half) * 128) * Kstr + (tt) * 64,        &As[(boff) + (((half) * 128) << 6) + (w << 9)]); \
  GLDS(aS + (size_t)((half) * 128 + 64) * Kstr + (tt) * 64,   &As[(boff) + (((half) * 128 + 64) << 6) + (w << 9)]); }
#define STG_B(boff, half, tt) { \
  GLDS(bS + (size_t)((half) * 128) * Kstr + (tt) * 64,        &Bs[(boff) + (((half) * 128) << 6) + (w << 9)]); \
  GLDS(bS + (size_t)((half) * 128 + 64) * Kstr + (tt) * 64,   &Bs[(boff) + (((half) * 128 + 64) << 6) + (w << 9)]); }
#define LDA_(dst, mh, ks) { _Pragma("unroll") for (int m_ = 0; m_ < 4; ++m_) \
  dst[m_] = *(const short8*)&As[so + ((wm * 128 + (mh) * 64 + m_ * 16 + lr) << 6) + ((((ks) * 4 + lq) ^ (lr & 7)) << 3)]; }
#define LDB_(dst, ks) { _Pragma("unroll") for (int n_ = 0; n_ < 4; ++n_) \
  dst[n_] = *(const short8*)&Bs[so + ((wn * 64 + n_ * 16 + lr) << 6) + ((((ks) * 4 + lq) ^ (lr & 7)) << 3)]; }
#define MMA(afr, mofs) do { __builtin_amdgcn_s_setprio(1); \
  _Pragma("unroll") for (int m_ = 0; m_ < 4; ++m_) { \
    _Pragma("unroll") for (int n_ = 0; n_ < 4; ++n_) \
      acc[(mofs) + m_][n_] = __builtin_amdgcn_mfma_f32_16x16x32_bf16(afr[m_], bfr[n_], acc[(mofs) + m_][n_], 0, 0, 0); } \
  __builtin_amdgcn_s_setprio(0); } while (0)

  f32x4 acc[8][4] = {};
  const int NT = K >> 6;

  // prologue: stage tile 0 fully + B0(1); wait for tile 0 only
  STG_A(0, 0, 0); STG_A(0, 1, 0); STG_B(0, 0, 0); STG_B(0, 1, 0);
  if (NT > 1) {
    STG_B(BUFE, 0, 1);
    asm volatile("s_waitcnt vmcnt(2)" ::: "memory");
  } else {
    asm volatile("s_waitcnt vmcnt(0)" ::: "memory");
  }
  BAR();

  for (int t = 0; t < NT; ++t) {
    const int so = (t & 1) * BUFE;
    const int nbuf = ((t + 1) & 1) * BUFE;
    short8 af0[4], af1[4], bfr[4];
    // ---- P0: af_lo ks0 + B ks0 ; stage B1(t+1) -> idle buf
    LDA_(af0, 0, 0);
    LDB_(bfr, 0);
    if (t + 1 < NT) { STG_B(nbuf, 1, t + 1); }
    BAR();
    MMA(af0, 0);
    BAR();
    // ---- P1: af_hi ks0 ; stage A0(t+1) -> idle buf
    LDA_(af1, 1, 0);
    if (t + 1 < NT) { STG_A(nbuf, 0, t + 1); }
    BAR();
    MMA(af1, 4);
    BAR();
    // ---- P2: af_lo ks1 + B ks1 ; stage A1(t+1) -> idle buf
    LDA_(af0, 0, 1);
    LDB_(bfr, 1);
    if (t + 1 < NT) { STG_A(nbuf, 1, t + 1); }
    BAR();
    MMA(af0, 0);
    BAR();
    // ---- P3: af_hi ks1 ; stage B0(t+2) -> current buf B region (dead after P2 barrier)
    LDA_(af1, 1, 1);
    if (t + 2 < NT) { STG_B(so, 0, t + 2); }
    BAR();
    MMA(af1, 4);
    if (t + 2 < NT) { asm volatile("s_waitcnt vmcnt(2)" ::: "memory"); }
    else            { asm volatile("s_waitcnt vmcnt(0)" ::: "memory"); }
    BAR();
  }

  #pragma unroll
  for (int m = 0; m < 8; ++m) {
    #pragma unroll
    for (int n = 0; n < 4; ++n) {
      int col = n0 + wn * 64 + n * 16 + lr;
      float bv = bias ? bias[col] : 0.0f;
      #pragma unroll
      for (int i = 0; i < 4; ++i) {
        size_t row = (size_t)(m0 + wm * 128 + m * 16 + lq * 4 + i);
        float v = acc[m][n][i] + bv;
        if (RELU) v = fmaxf(v, 0.0f);
        if (OT == 0) ((float*)Cout)[cofs + row * N + col] = v;
        else ((unsigned short*)Cout)[cofs + row * N + col] = f2bf(v);
      }
    }
  }
#undef STG_A
#undef STG_B
#undef LDA_
#undef LDB_
#undef MMA
}

// ---------------------------------------------------------------- bf16 TN MFMA GEMM (2-phase, BN<=128)
template<int BN, int OT, bool RELU, bool RES>
__global__ __launch_bounds__(256) void k_gemm_tn(
    const unsigned short* __restrict__ A, const unsigned short* __restrict__ BT,
    const float* __restrict__ bias, const float* __restrict__ R,
    void* __restrict__ Cout, int M, int N, int K) {
  constexpr int NF = BN / 32;
  __shared__ __attribute__((aligned(16))) unsigned short As[128 * 64];
  __shared__ __attribute__((aligned(16))) unsigned short Bs[BN * 64];
  int tid = threadIdx.x;
  int lane = tid & 63, w = tid >> 6;
  int lr = lane & 15, lq = lane >> 4;
  int m0 = blockIdx.x * 128, n0 = blockIdx.y * BN;
  int wr = (w >> 1) * 64, wc = (w & 1) * (BN / 2);

  int srow = w * 8 + (lane >> 3);
  int skoff = ((lane & 7) ^ (lane >> 3)) * 8;
  const unsigned short* a0 = A + (size_t)(m0 + srow) * K + skoff;
  const unsigned short* b0 = BT + (size_t)(n0 + srow) * K + skoff;

  f32x4 acc[4][NF] = {};

  for (int k0 = 0; k0 < K; k0 += 64) {
    __syncthreads();
    #pragma unroll
    for (int j = 0; j < 4; ++j)
      __builtin_amdgcn_global_load_lds(
          (const __attribute__((address_space(1))) void*)(a0 + (size_t)(j * 32) * K + k0),
          (__attribute__((address_space(3))) void*)(As + j * 2048 + w * 512), 16, 0, 0);
    #pragma unroll
    for (int j = 0; j < NF; ++j)
      __builtin_amdgcn_global_load_lds(
          (const __attribute__((address_space(1))) void*)(b0 + (size_t)(j * 32) * K + k0),
          (__attribute__((address_space(3))) void*)(Bs + j * 2048 + w * 512), 16, 0, 0);
    __syncthreads();
    short8 af[4][2], bf[NF][2];
    #pragma unroll
    for (int m = 0; m < 4; ++m)
      #pragma unroll
      for (int ks = 0; ks < 2; ++ks)
        af[m][ks] = *(const short8*)&As[(wr + m * 16 + lr) * 64 + (((ks * 4 + lq) ^ (lr & 7)) << 3)];
    #pragma unroll
    for (int n = 0; n < NF; ++n)
      #pragma unroll
      for (int ks = 0; ks < 2; ++ks)
        bf[n][ks] = *(const short8*)&Bs[(wc + n * 16 + lr) * 64 + (((ks * 4 + lq) ^ (lr & 7)) << 3)];
    #pragma unroll
    for (int ks = 0; ks < 2; ++ks)
      #pragma unroll
      for (int m = 0; m < 4; ++m)
        #pragma unroll
        for (int n = 0; n < NF; ++n)
          acc[m][n] = __builtin_amdgcn_mfma_f32_16x16x32_bf16(af[m][ks], bf[n][ks], acc[m][n], 0, 0, 0);
  }

  #pragma unroll
  for (int m = 0; m < 4; ++m) {
    #pragma unroll
    for (int n = 0; n < NF; ++n) {
      int col = n0 + wc + n * 16 + lr;
      float bv = bias ? bias[col] : 0.0f;
      #pragma unroll
      for (int i = 0; i < 4; ++i) {
        size_t row = (size_t)(m0 + wr + m * 16 + lq * 4 + i);
        float v = acc[m][n][i] + bv;
        if (RELU) v = fmaxf(v, 0.0f);
        if (RES)  v += R[row * N + col];
        if (OT == 0) ((float*)Cout)[row * N + col] = v;
        else ((unsigned short*)Cout)[row * N + col] = f2bf(v);
      }
    }
  }
}

// ---------------------------------------------------------------- legacy GEMM (fp32 B) for LM fallback
template<int OT, bool RELU, bool RES>
__global__ __launch_bounds__(256) void k_gemm_bf(
    const unsigned short* __restrict__ A, const float* __restrict__ W,
    const float* __restrict__ bias, const float* __restrict__ R,
    void* __restrict__ Cout, int M, int N, int K) {
  __shared__ unsigned short As[128][40];
  __shared__ unsigned short Bs[128][40];
  int tid = threadIdx.x;
  int lane = tid & 63, wid = tid >> 6;
  int m0 = blockIdx.x * 128, n0 = blockIdx.y * 128;
  int wr = (wid >> 1) * 64, wc = (wid & 1) * 64;
  f32x4 acc[4][4] = {};
  int a_row = tid >> 1, a_koff = (tid & 1) * 16;
  int b_nb = tid & 31, b_kb = (tid >> 5) * 4;
  int lr = lane & 15, lq = lane >> 4;
  for (int k0 = 0; k0 < K; k0 += 32) {
    const unsigned short* ap = A + (size_t)(m0 + a_row) * K + k0 + a_koff;
    uint4 av0 = *(const uint4*)ap;
    uint4 av1 = *(const uint4*)(ap + 8);
    float wv[4][4];
    #pragma unroll
    for (int dk = 0; dk < 4; ++dk) {
      const float* wrow = W + (size_t)(k0 + b_kb + dk) * N + n0 + b_nb;
      #pragma unroll
      for (int j = 0; j < 4; ++j) wv[j][dk] = wrow[32 * j];
    }
    __syncthreads();
    *(uint4*)&As[a_row][a_koff]     = av0;
    *(uint4*)&As[a_row][a_koff + 8] = av1;
    #pragma unroll
    for (int j = 0; j < 4; ++j) {
      ushort4 pk;
      pk.x = f2bf(wv[j][0]); pk.y = f2bf(wv[j][1]);
      pk.z = f2bf(wv[j][2]); pk.w = f2bf(wv[j][3]);
      *(ushort4*)&Bs[b_nb + 32 * j][b_kb] = pk;
    }
    __syncthreads();
    short8 af[4], bf[4];
    #pragma unroll
    for (int m = 0; m < 4; ++m) af[m] = *(const short8*)&As[wr + m * 16 + lr][lq * 8];
    #pragma unroll
    for (int n = 0; n < 4; ++n) bf[n] = *(const short8*)&Bs[wc + n * 16 + lr][lq * 8];
    #pragma unroll
    for (int m = 0; m < 4; ++m)
      #pragma unroll
      for (int n = 0; n < 4; ++n)
        acc[m][n] = __builtin_amdgcn_mfma_f32_16x16x32_bf16(af[m], bf[n], acc[m][n], 0, 0, 0);
  }
  #pragma unroll
  for (int m = 0; m < 4; ++m) {
    #pragma unroll
    for (int n = 0; n < 4; ++n) {
      int col = n0 + wc + n * 16 + lr;
      float bv = bias ? bias[col] : 0.0f;
      #pragma unroll
      for (int i = 0; i < 4; ++i) {
        size_t row = (size_t)(m0 + wr + m * 16 + lq * 4 + i);
        float v = acc[m][n][i] + bv;
        if (RELU) v = fmaxf(v, 0.0f);
        if (RES)  v += R[row * N + col];
        if (OT == 0) ((float*)Cout)[row * N + col] = v;
        else ((unsigned short*)Cout)[row * N + col] = f2bf(v);
      }
    }
  }
}

// ---------------------------------------------------------------- flash attention (bf16 MFMA)
// 4 waves x 32 q-rows; T14 async staging: tile t+1's K/V global loads issued
// right after the staging barrier, LDS-written at top of t+1.
__global__ __launch_bounds__(256) void k_fattn(
    const unsigned short* __restrict__ QKV, unsigned short* __restrict__ O) {
  __shared__ unsigned short Ks[64][72];
  __shared__ unsigned short Vs[64][74];
  __shared__ unsigned short Pl[4][32][72];
  int tid = threadIdx.x;
  int lane = tid & 63, wid = tid >> 6;
  int lr = lane & 15, lq = lane >> 4;
  int qt = blockIdx.x, bh = blockIdx.y;
  int b = bh >> 4, h = bh & 15;
  size_t base = ((size_t)b * T_) * QKVS_ + h * HS_;
  int q0w = qt * 128 + wid * 32;

  short8 qf[2][2];
  #pragma unroll
  for (int g = 0; g < 2; ++g)
    #pragma unroll
    for (int s = 0; s < 2; ++s)
      qf[g][s] = *(const short8*)(QKV + base + (size_t)(q0w + g * 16 + lr) * QKVS_ + s * 32 + lq * 8);

  f32x4 o_acc[2][4] = {};
  float mrun[2][4], lrun[2][4];
  #pragma unroll
  for (int g = 0; g < 2; ++g)
    #pragma unroll
    for (int i = 0; i < 4; ++i) { mrun[g][i] = -1e30f; lrun[g][i] = 0.0f; }
  const float sc = 0.03125f * 1.44269504f;
  int r = tid >> 2, cc = (tid & 3) * 16;
  int ntiles = 2 * qt + 2;

  uint4 kA0, kA1, vA0, vA1;
  {
    const unsigned short* kp = QKV + base + 1024 + (size_t)r * QKVS_ + cc;
    kA0 = *(const uint4*)kp; kA1 = *(const uint4*)(kp + 8);
    vA0 = *(const uint4*)(kp + 1024); vA1 = *(const uint4*)(kp + 1032);
  }

  for (int t = 0; t < ntiles; ++t) {
    __syncthreads();                         // prev tile's LDS reads done
    *(uint4*)&Ks[r][cc] = kA0;
    *(uint4*)&Ks[r][cc + 8] = kA1;
    unsigned short vt[16];
    *(uint4*)&vt[0] = vA0; *(uint4*)&vt[8] = vA1;
    #pragma unroll
    for (int j = 0; j < 16; ++j) Vs[cc + j][r] = vt[j];
    __syncthreads();                         // staging visible
    if (t + 1 < ntiles) {                    // async: hide under compute below
      const unsigned short* kp = QKV + base + 1024 + (size_t)((t + 1) * 64 + r) * QKVS_ + cc;
      kA0 = *(const uint4*)kp; kA1 = *(const uint4*)(kp + 8);
      vA0 = *(const uint4*)(kp + 1024); vA1 = *(const uint4*)(kp + 1032);
    }

    f32x4 sa[2][4] = {};
    #pragma unroll
    for (int nt = 0; nt < 4; ++nt)
      #pragma unroll
      for (int s = 0; s < 2; ++s) {
        short8 kf = *(const short8*)&Ks[nt * 16 + lr][s * 32 + lq * 8];
        sa[0][nt] = __builtin_amdgcn_mfma_f32_16x16x32_bf16(qf[0][s], kf, sa[0][nt], 0, 0, 0);
        sa[1][nt] = __builtin_amdgcn_mfma_f32_16x16x32_bf16(qf[1][s], kf, sa[1][nt], 0, 0, 0);
      }

    bool diag = (t >= 2 * qt);
    float p[2][4][4];
    #pragma unroll
    for (int g = 0; g < 2; ++g)
      #pragma unroll
      for (int nt = 0; nt < 4; ++nt)
        #pragma unroll
        for (int i = 0; i < 4; ++i) {
          float v = sa[g][nt][i] * sc;
          if (diag && (t * 64 + nt * 16 + lr > q0w + g * 16 + lq * 4 + i)) v = -1e30f;
          p[g][nt][i] = v;
        }
    #pragma unroll
    for (int g = 0; g < 2; ++g)
      #pragma unroll
      for (int i = 0; i < 4; ++i) {
        float v = fmaxf(fmaxf(p[g][0][i], p[g][1][i]), fmaxf(p[g][2][i], p[g][3][i]));
        #pragma unroll
        for (int o = 1; o < 16; o <<= 1) v = fmaxf(v, __shfl_xor(v, o));
        float mn = fmaxf(mrun[g][i], v);
        float corr = __builtin_amdgcn_exp2f(mrun[g][i] - mn);
        mrun[g][i] = mn;
        float ps = 0.0f;
        #pragma unroll
        for (int nt = 0; nt < 4; ++nt) {
          float pe = __builtin_amdgcn_exp2f(p[g][nt][i] - mn);
          p[g][nt][i] = pe;
          ps += pe;
        }
        lrun[g][i] = lrun[g][i] * corr + ps;
        #pragma unroll
        for (int dn = 0; dn < 4; ++dn) o_acc[g][dn][i] *= corr;
      }
    #pragma unroll
    for (int g = 0; g < 2; ++g)
      #pragma unroll
      for (int nt = 0; nt < 4; ++nt)
        #pragma unroll
        for (int i = 0; i < 4; ++i)
          Pl[wid][g * 16 + lq * 4 + i][nt * 16 + lr] = f2bf(p[g][nt][i]);
    __syncthreads();                         // order P writes before P reads

    #pragma unroll
    for (int s = 0; s < 2; ++s) {
      short8 pa0 = *(const short8*)&Pl[wid][lr][s * 32 + lq * 8];
      short8 pa1 = *(const short8*)&Pl[wid][16 + lr][s * 32 + lq * 8];
      #pragma unroll
      for (int dn = 0; dn < 4; ++dn) {
        short8 vf = *(const short8*)&Vs[dn * 16 + lr][s * 32 + lq * 8];
        o_acc[0][dn] = __builtin_amdgcn_mfma_f32_16x16x32_bf16(pa0, vf, o_acc[0][dn], 0, 0, 0);
        o_acc[1][dn] = __builtin_amdgcn_mfma_f32_16x16x32_bf16(pa1, vf, o_acc[1][dn], 0, 0, 0);
      }
    }
  }

  #pragma unroll
  for (int g = 0; g < 2; ++g)
    #pragma unroll
    for (int i = 0; i < 4; ++i) {
      float v = lrun[g][i];
      #pragma unroll
      for (int o = 1; o < 16; o <<= 1) v += __shfl_xor(v, o);
      lrun[g][i] = 1.0f / v;
    }
  #pragma unroll
  for (int g = 0; g < 2; ++g)
    #pragma unroll
    for (int dn = 0; dn < 4; ++dn)
      #pragma unroll
      for (int i = 0; i < 4; ++i) {
        size_t row = (size_t)(b * T_) + q0w + g * 16 + lq * 4 + i;
        O[row * E_ + h * HS_ + dn * 16 + lr] = f2bf(o_acc[g][dn][i] * lrun[g][i]);
      }
}

// ---------------------------------------------------------------- launch
extern "C" void kernel_launch(void* const* d_in, const int* in_sizes, int n_in,
                              void* d_out, int out_size, void* d_ws, size_t ws_size,
                              hipStream_t stream) {
  const int*   idx  = (const int*)d_in[0];
  const float* tok  = (const float*)d_in[1];
  const float* pos  = (const float*)d_in[2];
  const float* ln1g = (const float*)d_in[3];
  const float* ln1b = (const float*)d_in[4];
  const float* Wq   = (const float*)d_in[5];
  const float* Wk   = (const float*)d_in[6];
  const float* Wv   = (const float*)d_in[7];
  const float* Wo   = (const float*)d_in[8];
  const float* bo   = (const float*)d_in[9];
  const float* ln2g = (const float*)d_in[10];
  const float* ln2b = (const float*)d_in[11];
  const float* W1   = (const float*)d_in[12];
  const float* b1   = (const float*)d_in[13];
  const float* W2   = (const float*)d_in[14];
  const float* b2   = (const float*)d_in[15];
  const float* lnfg = (const float*)d_in[16];
  const float* lnfb = (const float*)d_in[17];
  const float* Wlm  = (const float*)d_in[18];
  const float* blm  = (const float*)d_in[19];

  char* scr = (char*)d_out;
  const size_t MB = 1024 * 1024;
  float*          xf    = (float*)(scr);                      // 16MB
  unsigned short* qkvb  = (unsigned short*)(scr + 16 * MB);   // 24MB
  unsigned short* ob    = (unsigned short*)(scr + 40 * MB);   // 8MB
  unsigned short* mh    = (unsigned short*)(scr + 48 * MB);   // 32MB
  unsigned short* wqkvT = (unsigned short*)(scr + 80 * MB);   // 48MB
  unsigned short* woT   = (unsigned short*)(scr + 128 * MB);  // 16MB
  unsigned short* w1T   = (unsigned short*)(scr + 144 * MB);  // 64MB
  unsigned short* w2T   = (unsigned short*)(scr + 208 * MB);  // 64MB
  float*          p2    = (float*)(scr + 280 * MB);           // 64MB split-K partials
  unsigned short* hb    = (unsigned short*)d_ws;              // 8MB
  unsigned short* wlmT  = (unsigned short*)((char*)d_ws + 8 * MB); // 65.5MB
  const size_t EE = (size_t)E_ * E_;
  bool lm_fast = ws_size >= 8 * MB + (size_t)V_ * E_ * 2 + 1024;

  k_embed<<<M_, 256, 0, stream>>>(idx, tok, pos, xf);

  k_wt<<<dim3(16, 16, L_), 256, 0, stream>>>(Wq, wqkvT,          E_, E_, EE, 3 * EE);
  k_wt<<<dim3(16, 16, L_), 256, 0, stream>>>(Wk, wqkvT + EE,     E_, E_, EE, 3 * EE);
  k_wt<<<dim3(16, 16, L_), 256, 0, stream>>>(Wv, wqkvT + 2 * EE, E_, E_, EE, 3 * EE);
  k_wt<<<dim3(16, 16, L_), 256, 0, stream>>>(Wo, woT,            E_, E_, EE, EE);
  k_wt<<<dim3(64, 16, L_), 256, 0, stream>>>(W1, w1T, E_, 4 * E_, 4 * EE, 4 * EE);
  k_wt<<<dim3(16, 64, L_), 256, 0, stream>>>(W2, w2T, 4 * E_, E_, 4 * EE, 4 * EE);
  if (lm_fast)
    k_wt<<<dim3(V_ / 64, 16, 1), 256, 0, stream>>>(Wlm, wlmT, E_, V_, 0, 0);

  for (int l = 0; l < L_; ++l) {
    k_ln_bf<<<M_, 256, 0, stream>>>(xf, ln1g + l * E_, ln1b + l * E_, hb);
    k_gemm_256<1, false, 0><<<16 * (QKVS_ / 256), 512, 0, stream>>>(
        hb, wqkvT + (size_t)l * 3 * EE, nullptr, qkvb, QKVS_, E_, E_);
    k_fattn<<<dim3(T_ / 128, B_ * H_), 256, 0, stream>>>(qkvb, ob);
    k_gemm_tn<64, 0, false, true><<<dim3(32, 16), 256, 0, stream>>>(
        ob, woT + (size_t)l * EE, bo + l * E_, xf, xf, M_, E_, E_);
    k_ln_bf<<<M_, 256, 0, stream>>>(xf, ln2g + l * E_, ln2b + l * E_, hb);
    k_gemm_256<1, true, 0><<<16 * (4 * E_ / 256), 512, 0, stream>>>(
        hb, w1T + (size_t)l * 4 * EE, b1 + (size_t)l * 4 * E_, mh, 4 * E_, E_, E_);
    // MLP2: split-K=4 -> partials -> fused reduce(+bias+residual)
    k_gemm_256<0, false, 2><<<256, 512, 0, stream>>>(
        mh, w2T + (size_t)l * 4 * EE, nullptr, p2, E_, E_, 4 * E_);
    k_red4<<<M_ * E_ / 1024, 256, 0, stream>>>(p2, b2 + l * E_, xf);
  }
  k_ln_bf<<<M_, 256, 0, stream>>>(xf, lnfg, lnfb, hb);
  if (lm_fast)
    k_gemm_256<0, false, 1><<<16 * (V_ / 256), 512, 0, stream>>>(
        hb, wlmT, blm, (float*)d_out, V_, E_, E_);
  else
    k_gemm_bf<0, false, false><<<dim3(32, V_ / 128), 256, 0, stream>>>(
        hb, Wlm, blm, nullptr, (float*)d_out, M_, V_, E_);
}

// Round 8
// 2503.002 us; speedup vs baseline: 11.8327x; 1.0171x over previous
//
#include <hip/hip_runtime.h>
#include <math.h>

#define L_ 8
#define H_ 16
#define E_ 1024
#define V_ 32000
#define B_ 4
#define T_ 1024
#define HS_ 64
#define M_ 4096   // B*T
#define QKVS_ 3072  // fused qkv row stride

typedef __attribute__((ext_vector_type(8))) short short8;
typedef __attribute__((ext_vector_type(4))) float f32x4;

__device__ __forceinline__ unsigned short f2bf(float f) {
  unsigned int u = __builtin_bit_cast(unsigned int, f);
  u += 0x7fffu + ((u >> 16) & 1u);          // RNE
  return (unsigned short)(u >> 16);
}

// ---------------------------------------------------------------- embed (fp32 x)
__global__ __launch_bounds__(256) void k_embed(
    const int* __restrict__ idx, const float* __restrict__ tok,
    const float* __restrict__ pos, float* __restrict__ x) {
  int bt = blockIdx.x;
  int t  = bt & (T_ - 1);
  int token = idx[bt];
  const float4* te = (const float4*)(tok + (size_t)token * E_);
  const float4* pe = (const float4*)(pos + (size_t)t * E_);
  float4* xo = (float4*)(x + (size_t)bt * E_);
  int i = threadIdx.x;
  float4 a = te[i], b = pe[i];
  xo[i] = make_float4(a.x + b.x, a.y + b.y, a.z + b.z, a.w + b.w);
}

// ---------------------------------------------------------------- weight transpose+convert
__global__ __launch_bounds__(256) void k_wt(
    const float* __restrict__ W, unsigned short* __restrict__ WT,
    int K, int N, size_t ss, size_t ds) {
  __shared__ unsigned short t[64][66];
  const float* Ws = W + (size_t)blockIdx.z * ss;
  unsigned short* Wd = WT + (size_t)blockIdx.z * ds;
  int n0 = blockIdx.x * 64, k0 = blockIdx.y * 64;
  int tid = threadIdx.x;
  int c = tid & 63, r4 = tid >> 6;
  #pragma unroll
  for (int i = 0; i < 16; ++i) {
    int kr = i * 4 + r4;
    t[kr][c] = f2bf(Ws[(size_t)(k0 + kr) * N + n0 + c]);
  }
  __syncthreads();
  #pragma unroll
  for (int i = 0; i < 16; ++i) {
    int nr = i * 4 + r4;
    Wd[(size_t)(n0 + nr) * K + k0 + c] = t[c][nr];
  }
}

// ---------------------------------------------------------------- layernorm (fp32 in, bf16 out)
__device__ __forceinline__ float blk_sum256(float v, float* red) {
  #pragma unroll
  for (int o = 1; o < 64; o <<= 1) v += __shfl_xor(v, o);
  int wid = threadIdx.x >> 6, lane = threadIdx.x & 63;
  if (lane == 0) red[wid] = v;
  __syncthreads();
  v = red[0] + red[1] + red[2] + red[3];
  __syncthreads();
  return v;
}

__global__ __launch_bounds__(256) void k_ln_bf(
    const float* __restrict__ X, const float* __restrict__ g,
    const float* __restrict__ b, unsigned short* __restrict__ Y) {
  __shared__ float red[4];
  int row = blockIdx.x;
  int i = threadIdx.x;
  float4 xv = ((const float4*)(X + (size_t)row * E_))[i];
  float s = xv.x + xv.y + xv.z + xv.w;
  s = blk_sum256(s, red);
  float mean = s * (1.0f / E_);
  float dx = xv.x - mean, dy = xv.y - mean, dz = xv.z - mean, dw = xv.w - mean;
  float vs = dx*dx + dy*dy + dz*dz + dw*dw;
  vs = blk_sum256(vs, red);
  float rstd = rsqrtf(vs * (1.0f / E_) + 1e-5f);
  float4 gv = ((const float4*)g)[i];
  float4 bv = ((const float4*)b)[i];
  ushort4 o;
  o.x = f2bf(dx * rstd * gv.x + bv.x);
  o.y = f2bf(dy * rstd * gv.y + bv.y);
  o.z = f2bf(dz * rstd * gv.z + bv.z);
  o.w = f2bf(dw * rstd * gv.w + bv.w);
  ((ushort4*)(Y + (size_t)row * E_))[i] = o;
}

// ---------------------------------------------------------------- fused split-K reduce + residual + next-LN
// One block per row: x[row] += sum4(partials)+bias; then LN(x[row]) -> hb (bf16).
__global__ __launch_bounds__(256) void k_red4ln(
    const float* __restrict__ p, const float* __restrict__ bias,
    float* __restrict__ xf, const float* __restrict__ g,
    const float* __restrict__ b, unsigned short* __restrict__ hb) {
  __shared__ float red[4];
  const int ME = M_ * E_;
  int row = blockIdx.x;
  int tid = threadIdx.x;
  int i = row * E_ + tid * 4;
  float4 a  = *(const float4*)(p + i);
  float4 b2 = *(const float4*)(p + ME + i);
  float4 c  = *(const float4*)(p + 2 * ME + i);
  float4 d  = *(const float4*)(p + 3 * ME + i);
  float4 bv = *(const float4*)(bias + tid * 4);
  float4 x  = *(float4*)(xf + i);
  x.x += a.x + b2.x + c.x + d.x + bv.x;
  x.y += a.y + b2.y + c.y + d.y + bv.y;
  x.z += a.z + b2.z + c.z + d.z + bv.z;
  x.w += a.w + b2.w + c.w + d.w + bv.w;
  *(float4*)(xf + i) = x;
  // fused LN of the row just produced
  float s = x.x + x.y + x.z + x.w;
  s = blk_sum256(s, red);
  float mean = s * (1.0f / E_);
  float dx = x.x - mean, dy = x.y - mean, dz = x.z - mean, dw = x.w - mean;
  float vs = dx*dx + dy*dy + dz*dz + dw*dw;
  vs = blk_sum256(vs, red);
  float rstd = rsqrtf(vs * (1.0f / E_) + 1e-5f);
  float4 gv = ((const float4*)g)[tid];
  float4 lb = ((const float4*)b)[tid];
  ushort4 o;
  o.x = f2bf(dx * rstd * gv.x + lb.x);
  o.y = f2bf(dy * rstd * gv.y + lb.y);
  o.z = f2bf(dz * rstd * gv.z + lb.z);
  o.w = f2bf(dw * rstd * gv.w + lb.w);
  ((ushort4*)(hb + (size_t)row * E_))[tid] = o;
}

// ---------------------------------------------------------------- 256x256 8-phase bf16 GEMM
// DEC: 0 = m-fastest (16 m-blocks), 1 = LM head (msub8-fastest, L2-locality), 2 = split-K=4.
#define BUFE 16384   // 256*64 elements per buffer per matrix

#define GLDS(src, dst) __builtin_amdgcn_global_load_lds( \
    (const __attribute__((address_space(1))) void*)(src), \
    (__attribute__((address_space(3))) void*)(dst), 16, 0, 0)

#define BAR() do { asm volatile("" ::: "memory"); __builtin_amdgcn_s_barrier(); \
                   asm volatile("" ::: "memory"); } while (0)

template<int OT, bool RELU, int DEC>
__global__ __launch_bounds__(512, 2) void k_gemm_256(
    const unsigned short* __restrict__ A, const unsigned short* __restrict__ BT,
    const float* __restrict__ bias, void* __restrict__ Cout, int N, int K, int Kstr) {
  __shared__ __attribute__((aligned(16))) unsigned short As[2 * BUFE];  // 64KB
  __shared__ __attribute__((aligned(16))) unsigned short Bs[2 * BUFE];  // 64KB
  int tid = threadIdx.x;
  int lane = tid & 63, w = tid >> 6;           // 8 waves
  int lr = lane & 15, lq = (lane >> 4) & 3;
  int wm = w >> 2, wn = w & 3;                 // 2 x 4 wave grid

  // bijective XCD swizzle (m204)
  int nwg = gridDim.x, orig = blockIdx.x;
  int qq = nwg >> 3, rr = nwg & 7;
  int xcd = orig & 7, lid = orig >> 3;
  int wg = (xcd < rr ? xcd * (qq + 1) : rr * (qq + 1) + (xcd - rr) * qq) + lid;
  int m0, n0, kofs = 0;
  size_t cofs = 0;
  if constexpr (DEC == 0) { m0 = (wg & 15) * 256; n0 = (wg >> 4) * 256; }
  else if constexpr (DEC == 1) {
    // msub(8) fastest -> concurrent blocks on an XCD share B-panels + an A-half
    int nbn = N >> 8;
    int msub = wg & 7;
    int rest = wg >> 3;
    int nb = rest % nbn;
    int msup = rest / nbn;
    m0 = (msup * 8 + msub) * 256;
    n0 = nb * 256;
  } else {
    int inner = wg & 63;
    m0 = (inner & 15) * 256; n0 = (inner >> 4) * 256;
    int ks = wg >> 6;
    kofs = ks * K;
    cofs = (size_t)ks * M_ * (size_t)N;
  }

  // staging source: chunk swizzle c8_src = (lane&7) ^ (lane>>3); dest linear
  int srow = w * 8 + (lane >> 3);
  int skoff = ((lane & 7) ^ (lane >> 3)) * 8;
  const unsigned short* aS = A + (size_t)(m0 + srow) * Kstr + kofs + skoff;
  const unsigned short* bS = BT + (size_t)(n0 + srow) * Kstr + kofs + skoff;

#define STG_A(boff, half, tt) { \
  GLDS(aS + (size_t)((half) * 128) * Kstr + (tt) * 64,        &As[(boff) + (((half) * 128) << 6) + (w << 9)]); \
  GLDS(aS + (size_t)((half) * 128 + 64) * Kstr + (tt) * 64,   &As[(boff) + (((half) * 128 + 64) << 6) + (w << 9)]); }
#define STG_B(boff, half, tt) { \
  GLDS(bS + (size_t)((half) * 128) * Kstr + (tt) * 64,        &Bs[(boff) + (((half) * 128) << 6) + (w << 9)]); \
  GLDS(bS + (size_t)((half) * 128 + 64) * Kstr + (tt) * 64,   &Bs[(boff) + (((half) * 128 + 64) << 6) + (w << 9)]); }
#define LDA_(dst, mh, ks) { _Pragma("unroll") for (int m_ = 0; m_ < 4; ++m_) \
  dst[m_] = *(const short8*)&As[so + ((wm * 128 + (mh) * 64 + m_ * 16 + lr) << 6) + ((((ks) * 4 + lq) ^ (lr & 7)) << 3)]; }
#define LDB_(dst, ks) { _Pragma("unroll") for (int n_ = 0; n_ < 4; ++n_) \
  dst[n_] = *(const short8*)&Bs[so + ((wn * 64 + n_ * 16 + lr) << 6) + ((((ks) * 4 + lq) ^ (lr & 7)) << 3)]; }
#define MMA(afr, mofs) do { __builtin_amdgcn_s_setprio(1); \
  _Pragma("unroll") for (int m_ = 0; m_ < 4; ++m_) { \
    _Pragma("unroll") for (int n_ = 0; n_ < 4; ++n_) \
      acc[(mofs) + m_][n_] = __builtin_amdgcn_mfma_f32_16x16x32_bf16(afr[m_], bfr[n_], acc[(mofs) + m_][n_], 0, 0, 0); } \
  __builtin_amdgcn_s_setprio(0); } while (0)

  f32x4 acc[8][4] = {};
  const int NT = K >> 6;

  // prologue: stage tile 0 fully + B0(1); wait for tile 0 only
  STG_A(0, 0, 0); STG_A(0, 1, 0); STG_B(0, 0, 0); STG_B(0, 1, 0);
  if (NT > 1) {
    STG_B(BUFE, 0, 1);
    asm volatile("s_waitcnt vmcnt(2)" ::: "memory");
  } else {
    asm volatile("s_waitcnt vmcnt(0)" ::: "memory");
  }
  BAR();

  for (int t = 0; t < NT; ++t) {
    const int so = (t & 1) * BUFE;
    const int nbuf = ((t + 1) & 1) * BUFE;
    short8 af0[4], af1[4], bfr[4];
    // ---- P0: af_lo ks0 + B ks0 ; stage B1(t+1) -> idle buf
    LDA_(af0, 0, 0);
    LDB_(bfr, 0);
    if (t + 1 < NT) { STG_B(nbuf, 1, t + 1); }
    BAR();
    MMA(af0, 0);
    BAR();
    // ---- P1: af_hi ks0 ; stage A0(t+1) -> idle buf
    LDA_(af1, 1, 0);
    if (t + 1 < NT) { STG_A(nbuf, 0, t + 1); }
    BAR();
    MMA(af1, 4);
    BAR();
    // ---- P2: af_lo ks1 + B ks1 ; stage A1(t+1) -> idle buf
    LDA_(af0, 0, 1);
    LDB_(bfr, 1);
    if (t + 1 < NT) { STG_A(nbuf, 1, t + 1); }
    BAR();
    MMA(af0, 0);
    BAR();
    // ---- P3: af_hi ks1 ; stage B0(t+2) -> current buf B region (dead after P2 barrier)
    LDA_(af1, 1, 1);
    if (t + 2 < NT) { STG_B(so, 0, t + 2); }
    BAR();
    MMA(af1, 4);
    if (t + 2 < NT) { asm volatile("s_waitcnt vmcnt(2)" ::: "memory"); }
    else            { asm volatile("s_waitcnt vmcnt(0)" ::: "memory"); }
    BAR();
  }

  #pragma unroll
  for (int m = 0; m < 8; ++m) {
    #pragma unroll
    for (int n = 0; n < 4; ++n) {
      int col = n0 + wn * 64 + n * 16 + lr;
      float bv = bias ? bias[col] : 0.0f;
      #pragma unroll
      for (int i = 0; i < 4; ++i) {
        size_t row = (size_t)(m0 + wm * 128 + m * 16 + lq * 4 + i);
        float v = acc[m][n][i] + bv;
        if (RELU) v = fmaxf(v, 0.0f);
        if (OT == 0) ((float*)Cout)[cofs + row * N + col] = v;
        else ((unsigned short*)Cout)[cofs + row * N + col] = f2bf(v);
      }
    }
  }
#undef STG_A
#undef STG_B
#undef LDA_
#undef LDB_
#undef MMA
}

// ---------------------------------------------------------------- bf16 TN MFMA GEMM (2-phase, BN<=128)
template<int BN, int OT, bool RELU, bool RES>
__global__ __launch_bounds__(256) void k_gemm_tn(
    const unsigned short* __restrict__ A, const unsigned short* __restrict__ BT,
    const float* __restrict__ bias, const float* __restrict__ R,
    void* __restrict__ Cout, int M, int N, int K) {
  constexpr int NF = BN / 32;
  __shared__ __attribute__((aligned(16))) unsigned short As[128 * 64];
  __shared__ __attribute__((aligned(16))) unsigned short Bs[BN * 64];
  int tid = threadIdx.x;
  int lane = tid & 63, w = tid >> 6;
  int lr = lane & 15, lq = lane >> 4;
  int m0 = blockIdx.x * 128, n0 = blockIdx.y * BN;
  int wr = (w >> 1) * 64, wc = (w & 1) * (BN / 2);

  int srow = w * 8 + (lane >> 3);
  int skoff = ((lane & 7) ^ (lane >> 3)) * 8;
  const unsigned short* a0 = A + (size_t)(m0 + srow) * K + skoff;
  const unsigned short* b0 = BT + (size_t)(n0 + srow) * K + skoff;

  f32x4 acc[4][NF] = {};

  for (int k0 = 0; k0 < K; k0 += 64) {
    __syncthreads();
    #pragma unroll
    for (int j = 0; j < 4; ++j)
      __builtin_amdgcn_global_load_lds(
          (const __attribute__((address_space(1))) void*)(a0 + (size_t)(j * 32) * K + k0),
          (__attribute__((address_space(3))) void*)(As + j * 2048 + w * 512), 16, 0, 0);
    #pragma unroll
    for (int j = 0; j < NF; ++j)
      __builtin_amdgcn_global_load_lds(
          (const __attribute__((address_space(1))) void*)(b0 + (size_t)(j * 32) * K + k0),
          (__attribute__((address_space(3))) void*)(Bs + j * 2048 + w * 512), 16, 0, 0);
    __syncthreads();
    short8 af[4][2], bf[NF][2];
    #pragma unroll
    for (int m = 0; m < 4; ++m)
      #pragma unroll
      for (int ks = 0; ks < 2; ++ks)
        af[m][ks] = *(const short8*)&As[(wr + m * 16 + lr) * 64 + (((ks * 4 + lq) ^ (lr & 7)) << 3)];
    #pragma unroll
    for (int n = 0; n < NF; ++n)
      #pragma unroll
      for (int ks = 0; ks < 2; ++ks)
        bf[n][ks] = *(const short8*)&Bs[(wc + n * 16 + lr) * 64 + (((ks * 4 + lq) ^ (lr & 7)) << 3)];
    #pragma unroll
    for (int ks = 0; ks < 2; ++ks)
      #pragma unroll
      for (int m = 0; m < 4; ++m)
        #pragma unroll
        for (int n = 0; n < NF; ++n)
          acc[m][n] = __builtin_amdgcn_mfma_f32_16x16x32_bf16(af[m][ks], bf[n][ks], acc[m][n], 0, 0, 0);
  }

  #pragma unroll
  for (int m = 0; m < 4; ++m) {
    #pragma unroll
    for (int n = 0; n < NF; ++n) {
      int col = n0 + wc + n * 16 + lr;
      float bv = bias ? bias[col] : 0.0f;
      #pragma unroll
      for (int i = 0; i < 4; ++i) {
        size_t row = (size_t)(m0 + wr + m * 16 + lq * 4 + i);
        float v = acc[m][n][i] + bv;
        if (RELU) v = fmaxf(v, 0.0f);
        if (RES)  v += R[row * N + col];
        if (OT == 0) ((float*)Cout)[row * N + col] = v;
        else ((unsigned short*)Cout)[row * N + col] = f2bf(v);
      }
    }
  }
}

// ---------------------------------------------------------------- legacy GEMM (fp32 B) for LM fallback
template<int OT, bool RELU, bool RES>
__global__ __launch_bounds__(256) void k_gemm_bf(
    const unsigned short* __restrict__ A, const float* __restrict__ W,
    const float* __restrict__ bias, const float* __restrict__ R,
    void* __restrict__ Cout, int M, int N, int K) {
  __shared__ unsigned short As[128][40];
  __shared__ unsigned short Bs[128][40];
  int tid = threadIdx.x;
  int lane = tid & 63, wid = tid >> 6;
  int m0 = blockIdx.x * 128, n0 = blockIdx.y * 128;
  int wr = (wid >> 1) * 64, wc = (wid & 1) * 64;
  f32x4 acc[4][4] = {};
  int a_row = tid >> 1, a_koff = (tid & 1) * 16;
  int b_nb = tid & 31, b_kb = (tid >> 5) * 4;
  int lr = lane & 15, lq = lane >> 4;
  for (int k0 = 0; k0 < K; k0 += 32) {
    const unsigned short* ap = A + (size_t)(m0 + a_row) * K + k0 + a_koff;
    uint4 av0 = *(const uint4*)ap;
    uint4 av1 = *(const uint4*)(ap + 8);
    float wv[4][4];
    #pragma unroll
    for (int dk = 0; dk < 4; ++dk) {
      const float* wrow = W + (size_t)(k0 + b_kb + dk) * N + n0 + b_nb;
      #pragma unroll
      for (int j = 0; j < 4; ++j) wv[j][dk] = wrow[32 * j];
    }
    __syncthreads();
    *(uint4*)&As[a_row][a_koff]     = av0;
    *(uint4*)&As[a_row][a_koff + 8] = av1;
    #pragma unroll
    for (int j = 0; j < 4; ++j) {
      ushort4 pk;
      pk.x = f2bf(wv[j][0]); pk.y = f2bf(wv[j][1]);
      pk.z = f2bf(wv[j][2]); pk.w = f2bf(wv[j][3]);
      *(ushort4*)&Bs[b_nb + 32 * j][b_kb] = pk;
    }
    __syncthreads();
    short8 af[4], bf[4];
    #pragma unroll
    for (int m = 0; m < 4; ++m) af[m] = *(const short8*)&As[wr + m * 16 + lr][lq * 8];
    #pragma unroll
    for (int n = 0; n < 4; ++n) bf[n] = *(const short8*)&Bs[wc + n * 16 + lr][lq * 8];
    #pragma unroll
    for (int m = 0; m < 4; ++m)
      #pragma unroll
      for (int n = 0; n < 4; ++n)
        acc[m][n] = __builtin_amdgcn_mfma_f32_16x16x32_bf16(af[m], bf[n], acc[m][n], 0, 0, 0);
  }
  #pragma unroll
  for (int m = 0; m < 4; ++m) {
    #pragma unroll
    for (int n = 0; n < 4; ++n) {
      int col = n0 + wc + n * 16 + lr;
      float bv = bias ? bias[col] : 0.0f;
      #pragma unroll
      for (int i = 0; i < 4; ++i) {
        size_t row = (size_t)(m0 + wr + m * 16 + lq * 4 + i);
        float v = acc[m][n][i] + bv;
        if (RELU) v = fmaxf(v, 0.0f);
        if (RES)  v += R[row * N + col];
        if (OT == 0) ((float*)Cout)[row * N + col] = v;
        else ((unsigned short*)Cout)[row * N + col] = f2bf(v);
      }
    }
  }
}

// ---------------------------------------------------------------- flash attention (bf16 MFMA)
__global__ __launch_bounds__(256) void k_fattn(
    const unsigned short* __restrict__ QKV, unsigned short* __restrict__ O) {
  __shared__ unsigned short Ks[64][72];
  __shared__ unsigned short Vs[64][74];
  __shared__ unsigned short Pl[4][32][72];
  int tid = threadIdx.x;
  int lane = tid & 63, wid = tid >> 6;
  int lr = lane & 15, lq = lane >> 4;
  int qt = blockIdx.x, bh = blockIdx.y;
  int b = bh >> 4, h = bh & 15;
  size_t base = ((size_t)b * T_) * QKVS_ + h * HS_;
  int q0w = qt * 128 + wid * 32;

  short8 qf[2][2];
  #pragma unroll
  for (int g = 0; g < 2; ++g)
    #pragma unroll
    for (int s = 0; s < 2; ++s)
      qf[g][s] = *(const short8*)(QKV + base + (size_t)(q0w + g * 16 + lr) * QKVS_ + s * 32 + lq * 8);

  f32x4 o_acc[2][4] = {};
  float mrun[2][4], lrun[2][4];
  #pragma unroll
  for (int g = 0; g < 2; ++g)
    #pragma unroll
    for (int i = 0; i < 4; ++i) { mrun[g][i] = -1e30f; lrun[g][i] = 0.0f; }
  const float sc = 0.03125f * 1.44269504f;
  int r = tid >> 2, cc = (tid & 3) * 16;
  int ntiles = 2 * qt + 2;

  uint4 kA0, kA1, vA0, vA1;
  {
    const unsigned short* kp = QKV + base + 1024 + (size_t)r * QKVS_ + cc;
    kA0 = *(const uint4*)kp; kA1 = *(const uint4*)(kp + 8);
    vA0 = *(const uint4*)(kp + 1024); vA1 = *(const uint4*)(kp + 1032);
  }

  for (int t = 0; t < ntiles; ++t) {
    __syncthreads();                         // prev tile's LDS reads done
    *(uint4*)&Ks[r][cc] = kA0;
    *(uint4*)&Ks[r][cc + 8] = kA1;
    unsigned short vt[16];
    *(uint4*)&vt[0] = vA0; *(uint4*)&vt[8] = vA1;
    #pragma unroll
    for (int j = 0; j < 16; ++j) Vs[cc + j][r] = vt[j];
    __syncthreads();                         // staging visible
    if (t + 1 < ntiles) {                    // async: hide under compute below
      const unsigned short* kp = QKV + base + 1024 + (size_t)((t + 1) * 64 + r) * QKVS_ + cc;
      kA0 = *(const uint4*)kp; kA1 = *(const uint4*)(kp + 8);
      vA0 = *(const uint4*)(kp + 1024); vA1 = *(const uint4*)(kp + 1032);
    }

    f32x4 sa[2][4] = {};
    #pragma unroll
    for (int nt = 0; nt < 4; ++nt)
      #pragma unroll
      for (int s = 0; s < 2; ++s) {
        short8 kf = *(const short8*)&Ks[nt * 16 + lr][s * 32 + lq * 8];
        sa[0][nt] = __builtin_amdgcn_mfma_f32_16x16x32_bf16(qf[0][s], kf, sa[0][nt], 0, 0, 0);
        sa[1][nt] = __builtin_amdgcn_mfma_f32_16x16x32_bf16(qf[1][s], kf, sa[1][nt], 0, 0, 0);
      }

    bool diag = (t >= 2 * qt);
    float p[2][4][4];
    #pragma unroll
    for (int g = 0; g < 2; ++g)
      #pragma unroll
      for (int nt = 0; nt < 4; ++nt)
        #pragma unroll
        for (int i = 0; i < 4; ++i) {
          float v = sa[g][nt][i] * sc;
          if (diag && (t * 64 + nt * 16 + lr > q0w + g * 16 + lq * 4 + i)) v = -1e30f;
          p[g][nt][i] = v;
        }
    #pragma unroll
    for (int g = 0; g < 2; ++g)
      #pragma unroll
      for (int i = 0; i < 4; ++i) {
        float v = fmaxf(fmaxf(p[g][0][i], p[g][1][i]), fmaxf(p[g][2][i], p[g][3][i]));
        #pragma unroll
        for (int o = 1; o < 16; o <<= 1) v = fmaxf(v, __shfl_xor(v, o));
        float mn = fmaxf(mrun[g][i], v);
        float corr = __builtin_amdgcn_exp2f(mrun[g][i] - mn);
        mrun[g][i] = mn;
        float ps = 0.0f;
        #pragma unroll
        for (int nt = 0; nt < 4; ++nt) {
          float pe = __builtin_amdgcn_exp2f(p[g][nt][i] - mn);
          p[g][nt][i] = pe;
          ps += pe;
        }
        lrun[g][i] = lrun[g][i] * corr + ps;
        #pragma unroll
        for (int dn = 0; dn < 4; ++dn) o_acc[g][dn][i] *= corr;
      }
    #pragma unroll
    for (int g = 0; g < 2; ++g)
      #pragma unroll
      for (int nt = 0; nt < 4; ++nt)
        #pragma unroll
        for (int i = 0; i < 4; ++i)
          Pl[wid][g * 16 + lq * 4 + i][nt * 16 + lr] = f2bf(p[g][nt][i]);
    __syncthreads();                         // order P writes before P reads

    #pragma unroll
    for (int s = 0; s < 2; ++s) {
      short8 pa0 = *(const short8*)&Pl[wid][lr][s * 32 + lq * 8];
      short8 pa1 = *(const short8*)&Pl[wid][16 + lr][s * 32 + lq * 8];
      #pragma unroll
      for (int dn = 0; dn < 4; ++dn) {
        short8 vf = *(const short8*)&Vs[dn * 16 + lr][s * 32 + lq * 8];
        o_acc[0][dn] = __builtin_amdgcn_mfma_f32_16x16x32_bf16(pa0, vf, o_acc[0][dn], 0, 0, 0);
        o_acc[1][dn] = __builtin_amdgcn_mfma_f32_16x16x32_bf16(pa1, vf, o_acc[1][dn], 0, 0, 0);
      }
    }
  }

  #pragma unroll
  for (int g = 0; g < 2; ++g)
    #pragma unroll
    for (int i = 0; i < 4; ++i) {
      float v = lrun[g][i];
      #pragma unroll
      for (int o = 1; o < 16; o <<= 1) v += __shfl_xor(v, o);
      lrun[g][i] = 1.0f / v;
    }
  #pragma unroll
  for (int g = 0; g < 2; ++g)
    #pragma unroll
    for (int dn = 0; dn < 4; ++dn)
      #pragma unroll
      for (int i = 0; i < 4; ++i) {
        size_t row = (size_t)(b * T_) + q0w + g * 16 + lq * 4 + i;
        O[row * E_ + h * HS_ + dn * 16 + lr] = f2bf(o_acc[g][dn][i] * lrun[g][i]);
      }
}

// ---------------------------------------------------------------- launch
extern "C" void kernel_launch(void* const* d_in, const int* in_sizes, int n_in,
                              void* d_out, int out_size, void* d_ws, size_t ws_size,
                              hipStream_t stream) {
  const int*   idx  = (const int*)d_in[0];
  const float* tok  = (const float*)d_in[1];
  const float* pos  = (const float*)d_in[2];
  const float* ln1g = (const float*)d_in[3];
  const float* ln1b = (const float*)d_in[4];
  const float* Wq   = (const float*)d_in[5];
  const float* Wk   = (const float*)d_in[6];
  const float* Wv   = (const float*)d_in[7];
  const float* Wo   = (const float*)d_in[8];
  const float* bo   = (const float*)d_in[9];
  const float* ln2g = (const float*)d_in[10];
  const float* ln2b = (const float*)d_in[11];
  const float* W1   = (const float*)d_in[12];
  const float* b1   = (const float*)d_in[13];
  const float* W2   = (const float*)d_in[14];
  const float* b2   = (const float*)d_in[15];
  const float* lnfg = (const float*)d_in[16];
  const float* lnfb = (const float*)d_in[17];
  const float* Wlm  = (const float*)d_in[18];
  const float* blm  = (const float*)d_in[19];

  char* scr = (char*)d_out;
  const size_t MB = 1024 * 1024;
  float*          xf    = (float*)(scr);                      // 16MB
  unsigned short* qkvb  = (unsigned short*)(scr + 16 * MB);   // 24MB
  unsigned short* ob    = (unsigned short*)(scr + 40 * MB);   // 8MB
  unsigned short* mh    = (unsigned short*)(scr + 48 * MB);   // 32MB
  unsigned short* wqkvT = (unsigned short*)(scr + 80 * MB);   // 48MB
  unsigned short* woT   = (unsigned short*)(scr + 128 * MB);  // 16MB
  unsigned short* w1T   = (unsigned short*)(scr + 144 * MB);  // 64MB
  unsigned short* w2T   = (unsigned short*)(scr + 208 * MB);  // 64MB
  float*          p2    = (float*)(scr + 280 * MB);           // 64MB split-K partials
  unsigned short* hb    = (unsigned short*)d_ws;              // 8MB
  unsigned short* wlmT  = (unsigned short*)((char*)d_ws + 8 * MB); // 65.5MB
  const size_t EE = (size_t)E_ * E_;
  bool lm_fast = ws_size >= 8 * MB + (size_t)V_ * E_ * 2 + 1024;

  k_embed<<<M_, 256, 0, stream>>>(idx, tok, pos, xf);

  k_wt<<<dim3(16, 16, L_), 256, 0, stream>>>(Wq, wqkvT,          E_, E_, EE, 3 * EE);
  k_wt<<<dim3(16, 16, L_), 256, 0, stream>>>(Wk, wqkvT + EE,     E_, E_, EE, 3 * EE);
  k_wt<<<dim3(16, 16, L_), 256, 0, stream>>>(Wv, wqkvT + 2 * EE, E_, E_, EE, 3 * EE);
  k_wt<<<dim3(16, 16, L_), 256, 0, stream>>>(Wo, woT,            E_, E_, EE, EE);
  k_wt<<<dim3(64, 16, L_), 256, 0, stream>>>(W1, w1T, E_, 4 * E_, 4 * EE, 4 * EE);
  k_wt<<<dim3(16, 64, L_), 256, 0, stream>>>(W2, w2T, 4 * E_, E_, 4 * EE, 4 * EE);
  if (lm_fast)
    k_wt<<<dim3(V_ / 64, 16, 1), 256, 0, stream>>>(Wlm, wlmT, E_, V_, 0, 0);

  // ln1 of layer 0; all subsequent ln1/lnf are fused into k_red4ln
  k_ln_bf<<<M_, 256, 0, stream>>>(xf, ln1g, ln1b, hb);

  for (int l = 0; l < L_; ++l) {
    k_gemm_256<1, false, 0><<<16 * (QKVS_ / 256), 512, 0, stream>>>(
        hb, wqkvT + (size_t)l * 3 * EE, nullptr, qkvb, QKVS_, E_, E_);
    k_fattn<<<dim3(T_ / 128, B_ * H_), 256, 0, stream>>>(qkvb, ob);
    k_gemm_tn<64, 0, false, true><<<dim3(32, 16), 256, 0, stream>>>(
        ob, woT + (size_t)l * EE, bo + l * E_, xf, xf, M_, E_, E_);
    k_ln_bf<<<M_, 256, 0, stream>>>(xf, ln2g + l * E_, ln2b + l * E_, hb);
    k_gemm_256<1, true, 0><<<16 * (4 * E_ / 256), 512, 0, stream>>>(
        hb, w1T + (size_t)l * 4 * EE, b1 + (size_t)l * 4 * E_, mh, 4 * E_, E_, E_);
    // MLP2: split-K=4 -> partials -> fused reduce(+bias+residual) + next-layer LN
    k_gemm_256<0, false, 2><<<256, 512, 0, stream>>>(
        mh, w2T + (size_t)l * 4 * EE, nullptr, p2, E_, E_, 4 * E_);
    const float* ng = (l + 1 < L_) ? (ln1g + (size_t)(l + 1) * E_) : lnfg;
    const float* nb = (l + 1 < L_) ? (ln1b + (size_t)(l + 1) * E_) : lnfb;
    k_red4ln<<<M_, 256, 0, stream>>>(p2, b2 + l * E_, xf, ng, nb, hb);
  }
  // hb now holds lnf(x)
  if (lm_fast)
    k_gemm_256<0, false, 1><<<16 * (V_ / 256), 512, 0, stream>>>(
        hb, wlmT, blm, (float*)d_out, V_, E_, E_);
  else
    k_gemm_bf<0, false, false><<<dim3(32, V_ / 128), 256, 0, stream>>>(
        hb, Wlm, blm, nullptr, (float*)d_out, M_, V_, E_);
}